// Round 4
// baseline (132.921 us; speedup 1.0000x reference)
//
#include <hip/hip_runtime.h>
#include <math.h>

// Problem constants: B,F,C,H,W,D
constexpr int B_ = 2, F_ = 2, C_ = 64, H_ = 32, W_ = 104, D_ = 96;
constexpr int HW_ = H_ * W_;             // 3328
#define EPSF 1e-7f

// Workspace layout:
//   lfT  [B,F,H,W,C]  bf16 (ushort)  channel-last lookup feats  -- R12: bf16 halves L2 corner traffic
//   curT [B,H,W,C]    f32            channel-last current feats
constexpr size_t LFT_ELEMS  = (size_t)B_ * F_ * HW_ * C_;   // 851968 ushorts = 1,703,936 B
constexpr size_t CURT_OFF_F = LFT_ELEMS / 2;                // 425984 floats (byte offset identical)

constexpr int NT_BLKS = (HW_ / 32) * (C_ / 32) * (B_ * F_ + B_);  // 1248
constexpr int PXB   = 4;        // pixels per block — 16B stores + reuse sweet spot (R10: PXB=2 => 9x write amp)
constexpr int XT_   = W_ / PXB; // 26 x-tiles
// R14: depth-split — each block covers 48 of 96 depths; 2x blocks => 8 blocks/CU
// resident (was 6) + tail fill. R13 lesson: register pipelines spill (conditional
// defs -> scratch, +42MB WRITE); buy latency hiding with occupancy instead.
constexpr int DL_   = 48;       // depths per block
constexpr int DPAD  = DL_ + 1;  // 49: float4 row stride
constexpr int DPADI = DL_ + 4;  // 52: int row stride (multiple of 4 -> int4 rows 16B aligned)

// DPP butterfly add over 16-lane group — bit-identical to __shfl_xor chain
// (only commutes IEEE add operands). VALU-only: no ds_swizzle latency.
template<int CTRL>
__device__ __forceinline__ float dpp_add(float x) {
    int y = __builtin_amdgcn_update_dpp(0, __float_as_int(x), CTRL, 0xf, 0xf, true);
    return x + __int_as_float(y);
}
__device__ __forceinline__ float group16_sum(float s) {
    s = dpp_add<0xB1>(s);    // quad_perm(1,0,3,2)  == + lane^1
    s = dpp_add<0x4E>(s);    // quad_perm(2,3,0,1)  == + lane^2
    s = dpp_add<0x141>(s);   // row_half_mirror     == + lane^4-equiv
    s = dpp_add<0x140>(s);   // row_mirror          == + lane^8-equiv
    return s;
}

// f32 -> bf16 with round-to-nearest-even (features are finite; no NaN path needed)
__device__ __forceinline__ ushort f2bf(float f) {
    unsigned u = __float_as_uint(f);
    u += 0x7FFFu + ((u >> 16) & 1u);
    return (ushort)(u >> 16);
}
// unpack 4 consecutive bf16 channels (one uint2) to float4
__device__ __forceinline__ float4 bf4(uint2 q) {
    return make_float4(__uint_as_float(q.x << 16),
                       __uint_as_float(q.x & 0xffff0000u),
                       __uint_as_float(q.y << 16),
                       __uint_as_float(q.y & 0xffff0000u));
}

// ---------------------------------------------------------------------------
// Prep: channel-last transpose [C, HW] -> [HW, C] for 6 slices.
// lf slices (0..3) are written as bf16; cur slices (4..5) stay f32.
__global__ __launch_bounds__(256) void prep_kernel(
        const float* __restrict__ cur, const float* __restrict__ lf,
        float* __restrict__ ws) {
    __shared__ float tile[32][33];
    int bid = blockIdx.x;
    int slice = bid / 208;            // 208 = 104 n-blocks * 2 c-blocks
    int rem   = bid % 208;
    int nb = rem % 104, cb = rem / 104;
    const float* inS = (slice < B_ * F_)
        ? lf  + (size_t)slice * C_ * HW_
        : cur + (size_t)(slice - B_ * F_) * C_ * HW_;
    int t = threadIdx.x;
    int tx = t & 31, ty = t >> 5;
    int n0 = nb * 32, c0 = cb * 32;
    #pragma unroll
    for (int k = 0; k < 32; k += 8)
        tile[ty + k][tx] = inS[(size_t)(c0 + ty + k) * HW_ + n0 + tx];
    __syncthreads();
    if (slice < B_ * F_) {
        ushort* outS = (ushort*)ws + (size_t)slice * HW_ * C_;
        #pragma unroll
        for (int k = 0; k < 32; k += 8)
            outS[(size_t)(n0 + ty + k) * C_ + c0 + tx] = f2bf(tile[tx][ty + k]);
    } else {
        float* outS = ws + CURT_OFF_F + (size_t)(slice - B_ * F_) * HW_ * C_;
        #pragma unroll
        for (int k = 0; k < 32; k += 8)
            outS[(size_t)(n0 + ty + k) * C_ + c0 + tx] = tile[tx][ty + k];
    }
}

// ---------------------------------------------------------------------------
// Mega kernel (R14): block = (b, y, xt, dhalf) covering 4 px * 48 depths * 2
// frames. 256 threads = 4 quarters x (16 lanes x 4 px); each quarter walks 12
// depths. Phase A: 192 projections -> LDS {offset, float4 weights} (bit-
// identical FP op order — mask-critical, do not touch). Phase B: R12-form
// consume-time deduped bf16 corner loads + DPP channel reduce; cost stored
// RAW (zeros kept) straight to out. Missing-fill moved to fixup_kernel.
__global__ __launch_bounds__(256, 8) void mega_kernel(
        const float* __restrict__ poses, const float* __restrict__ K,
        const float* __restrict__ invK, const float* __restrict__ depth_bins,
        const float* __restrict__ ws, float* __restrict__ out) {
    int t   = threadIdx.x;
    int bid = blockIdx.x;
    int xt  = bid % XT_;  int r = bid / XT_;
    int dhalf = r & 1;    r >>= 1;      // adjacent bids share (b,y,xt) -> L2 locality
    int y   = r % H_;
    int b   = r / H_;
    int d0g = dhalf * DL_;              // global depth base of this block

    if (y < 2 || y >= H_ - 2) {
        // whole row masked: cost 0 everywhere; fixup max over column = 0 -> stays 0
        for (int k = t; k < PXB * DL_; k += 256) {
            int d = d0g + (k >> 2), px = k & 3;
            out[((size_t)(b * D_ + d) * H_ + y) * W_ + xt * PXB + px] = 0.0f;
        }
        return;   // block-uniform exit
    }

    __shared__ alignas(16) int offsL[F_][PXB][DPADI];
    __shared__ float4 wtsL [F_][PXB][DPAD];

    // ---- Phase A: projections (FP op order identical to R9/R11) ----
    {
        // px = t & 3 — invariant. Hoist cam/interior.
        int pxA = t & 3;
        int xA  = xt * PXB + pxA;
        const float* iK = invK + (size_t)b * 16;
        float xf = (float)xA, yf = (float)y;
        float cam0 = __fmul_rn(iK[0], xf); cam0 = __fmaf_rn(iK[1], yf, cam0); cam0 = __fmaf_rn(iK[2],  1.0f, cam0);
        float cam1 = __fmul_rn(iK[4], xf); cam1 = __fmaf_rn(iK[5], yf, cam1); cam1 = __fmaf_rn(iK[6],  1.0f, cam1);
        float cam2 = __fmul_rn(iK[8], xf); cam2 = __fmaf_rn(iK[9], yf, cam2); cam2 = __fmaf_rn(iK[10], 1.0f, cam2);
        bool interior = (xA >= 2) && (xA <= W_ - 3);   // y already interior

        #pragma unroll
        for (int f = 0; f < F_; ++f) {
            const float* Kb   = K + (size_t)b * 16;
            const float* pose = poses + (size_t)(b * F_ + f) * 16;
            float P[12];
            #pragma unroll
            for (int i = 0; i < 3; ++i) {
                #pragma unroll
                for (int k = 0; k < 4; ++k) {
                    float acc = __fmul_rn(Kb[i*4+0], pose[0*4+k]);
                    acc = __fmaf_rn(Kb[i*4+1], pose[1*4+k], acc);
                    acc = __fmaf_rn(Kb[i*4+2], pose[2*4+k], acc);
                    acc = __fmaf_rn(Kb[i*4+3], pose[3*4+k], acc);
                    P[i*4+k] = acc;
                }
            }
            float vs = 0.f;
            #pragma unroll
            for (int j = 0; j < 16; ++j) vs += pose[j];
            bool valid = (vs != 0.f);

            // 192 records = dd*4 + px, single pass (threads 192..255 idle)
            if (t < PXB * DL_) {
                int dd = t >> 2;                       // local depth
                float depth = depth_bins[d0g + dd];
                float p0 = __fmul_rn(depth, cam0);
                float p1 = __fmul_rn(depth, cam1);
                float p2 = __fmul_rn(depth, cam2);
                float c0 = __fmul_rn(P[0], p0); c0 = __fmaf_rn(P[1], p1, c0); c0 = __fmaf_rn(P[2],  p2, c0); c0 = __fmaf_rn(P[3],  1.0f, c0);
                float c1 = __fmul_rn(P[4], p0); c1 = __fmaf_rn(P[5], p1, c1); c1 = __fmaf_rn(P[6],  p2, c1); c1 = __fmaf_rn(P[7],  1.0f, c1);
                float c2 = __fmul_rn(P[8], p0); c2 = __fmaf_rn(P[9], p1, c2); c2 = __fmaf_rn(P[10], p2, c2); c2 = __fmaf_rn(P[11], 1.0f, c2);
                float denom = __fadd_rn(c2, EPSF);
                float gx = c0 / denom;   // IEEE div — mask-critical
                float gy = c1 / denom;
                bool m = valid && interior && (gx >= 2.0f) && (gx <= (float)(W_ - 2))
                                           && (gy >= 2.0f) && (gy <= (float)(H_ - 2));
                if (m) {
                    float x0f = floorf(gx), y0f = floorf(gy);
                    int   x0  = (int)x0f,   y0  = (int)y0f;
                    float wx1 = gx - x0f, wy1 = gy - y0f;
                    float wx0 = 1.f - wx1, wy0 = 1.f - wy1;
                    wtsL[f][pxA][dd] = make_float4(wy0 * wx0, wy0 * wx1,
                                                   wy1 * wx0, wy1 * wx1);
                    offsL[f][pxA][dd] = (y0 * W_ + x0) * C_;   // element offset (ushort units)
                } else {
                    offsL[f][pxA][dd] = -1;
                    // NaN-safety: weights MUST be finite (diff = s*0; 0*NaN=NaN).
                    wtsL[f][pxA][dd] = make_float4(0.f, 0.f, 0.f, 0.f);
                }
            }
        }
    }
    __syncthreads();

    // ---- Phase B: deduped bf16 corner loads + DPP channel reduce (R12 form) ----
    {
        int lane = t & 15, px = (t >> 4) & 3, quarter = t >> 6;  // quarter in [0,4)
        int x = xt * PXB + px;
        const float4 cv = *(const float4*)(ws + CURT_OFF_F
                            + ((size_t)((b * H_ + y) * W_ + x)) * C_ + lane * 4);
        // two bases per frame: row y0 and row y0+1 (col x0+1 is +C_ = 128B imm)
        const ushort* lfbase = (const ushort*)ws;
        const ushort* lf0a = lfbase + (size_t)(b * F_ + 0) * HW_ * C_ + lane * 4;
        const ushort* lf0b = lf0a + W_ * C_;
        const ushort* lf1a = lfbase + (size_t)(b * F_ + 1) * HW_ * C_ + lane * 4;
        const ushort* lf1b = lf1a + W_ * C_;

        float4 cc0[4], cc1[4];
        int oprev0 = -1, oprev1 = -1;
        #pragma unroll
        for (int k = 0; k < 4; ++k)
            cc0[k] = cc1[k] = make_float4(0.f, 0.f, 0.f, 0.f);

        size_t outbase = ((size_t)(b * D_ + d0g) * H_ + y) * W_ + x;
        int dbeg = quarter * (DL_ / 4);                  // 12 depths per quarter
        for (int ki4 = 0; ki4 < DL_ / 16; ++ki4) {       // 3 groups of 4 depths
            int dc4 = dbeg + ki4 * 4;
            int4 oq0 = *(const int4*)&offsL[0][px][dc4]; // one ds_read_b128 / frame / 4 depths
            int4 oq1 = *(const int4*)&offsL[1][px][dc4];
            int oa0[4] = {oq0.x, oq0.y, oq0.z, oq0.w};   // static-indexed (unrolled j)
            int oa1[4] = {oq1.x, oq1.y, oq1.z, oq1.w};

            #pragma unroll
            for (int j = 0; j < 4; ++j) {
                int dc = dc4 + j;
                int    oc0 = oa0[j],          oc1 = oa1[j];
                float4 wc0 = wtsL[0][px][dc], wc1 = wtsL[1][px][dc];

                float costsum = 0.f, counts = 0.f;
                // f = 0
                {
                    bool m = (oc0 >= 0);
                    if (m && oc0 != oprev0) {     // 16-lane-group-uniform branch
                        cc0[0] = bf4(*(const uint2*)(lf0a + oc0));
                        cc0[1] = bf4(*(const uint2*)(lf0a + oc0 + C_));
                        cc0[2] = bf4(*(const uint2*)(lf0b + oc0));
                        cc0[3] = bf4(*(const uint2*)(lf0b + oc0 + C_));
                        oprev0 = oc0;
                    }
                    float a0 = __fmaf_rn(cc0[0].x, wc0.x, __fmaf_rn(cc0[1].x, wc0.y, __fmaf_rn(cc0[2].x, wc0.z, __fmaf_rn(cc0[3].x, wc0.w, -cv.x))));
                    float a1 = __fmaf_rn(cc0[0].y, wc0.x, __fmaf_rn(cc0[1].y, wc0.y, __fmaf_rn(cc0[2].y, wc0.z, __fmaf_rn(cc0[3].y, wc0.w, -cv.y))));
                    float a2 = __fmaf_rn(cc0[0].z, wc0.x, __fmaf_rn(cc0[1].z, wc0.y, __fmaf_rn(cc0[2].z, wc0.z, __fmaf_rn(cc0[3].z, wc0.w, -cv.z))));
                    float a3 = __fmaf_rn(cc0[0].w, wc0.x, __fmaf_rn(cc0[1].w, wc0.y, __fmaf_rn(cc0[2].w, wc0.z, __fmaf_rn(cc0[3].w, wc0.w, -cv.w))));
                    float s = (fabsf(a0) + fabsf(a1)) + (fabsf(a2) + fabsf(a3));
                    s = group16_sum(s);
                    float diff = __fmul_rn(s, 1.0f / 64.0f) * (m ? 1.0f : 0.0f);
                    costsum += diff;
                    counts  += (diff > 0.f) ? 1.0f : 0.0f;
                }
                // f = 1
                {
                    bool m = (oc1 >= 0);
                    if (m && oc1 != oprev1) {
                        cc1[0] = bf4(*(const uint2*)(lf1a + oc1));
                        cc1[1] = bf4(*(const uint2*)(lf1a + oc1 + C_));
                        cc1[2] = bf4(*(const uint2*)(lf1b + oc1));
                        cc1[3] = bf4(*(const uint2*)(lf1b + oc1 + C_));
                        oprev1 = oc1;
                    }
                    float a0 = __fmaf_rn(cc1[0].x, wc1.x, __fmaf_rn(cc1[1].x, wc1.y, __fmaf_rn(cc1[2].x, wc1.z, __fmaf_rn(cc1[3].x, wc1.w, -cv.x))));
                    float a1 = __fmaf_rn(cc1[0].y, wc1.x, __fmaf_rn(cc1[1].y, wc1.y, __fmaf_rn(cc1[2].y, wc1.z, __fmaf_rn(cc1[3].y, wc1.w, -cv.y))));
                    float a2 = __fmaf_rn(cc1[0].z, wc1.x, __fmaf_rn(cc1[1].z, wc1.y, __fmaf_rn(cc1[2].z, wc1.z, __fmaf_rn(cc1[3].z, wc1.w, -cv.z))));
                    float a3 = __fmaf_rn(cc1[0].w, wc1.x, __fmaf_rn(cc1[1].w, wc1.y, __fmaf_rn(cc1[2].w, wc1.z, __fmaf_rn(cc1[3].w, wc1.w, -cv.w))));
                    float s = (fabsf(a0) + fabsf(a1)) + (fabsf(a2) + fabsf(a3));
                    s = group16_sum(s);
                    float diff = __fmul_rn(s, 1.0f / 64.0f) * (m ? 1.0f : 0.0f);
                    costsum += diff;
                    counts  += (diff > 0.f) ? 1.0f : 0.0f;
                }
                // cost via fast rcp: ~1e-7 rel err (bf16 threshold 2.9e-2), and
                // EXACT zero preserved (costsum==0 -> 0*rcp(eps)=0) so the ==0.0
                // missing-fill semantics are unchanged.
                float cost = costsum * __builtin_amdgcn_rcpf(__fadd_rn(counts, EPSF));
                // raw store (zeros kept); 4 px-group lane0s of a wave store
                // consecutive x -> one 16B segment per wave-store.
                if (lane == 0) out[outbase + (size_t)dc * HW_] = cost;
            }
        }
    }
}

// ---------------------------------------------------------------------------
// Fixup: per (b,y,x) column over d — cmax = max(cost), cost==0 -> cmax.
// Exact-max, order-free; ==0.0 semantics identical to in-block Phase C.
// Tiny: 5 MB L2-hot traffic, runs after mega on the same stream.
__global__ __launch_bounds__(128) void fixup_kernel(float* __restrict__ out) {
    int by = blockIdx.x;            // [0, B*H)
    int b = by / H_, y = by % H_;
    int x = threadIdx.x;
    if (x >= W_) return;
    size_t base = ((size_t)(b * D_) * H_ + y) * W_ + x;
    float cm = 0.f;
    #pragma unroll 8
    for (int d = 0; d < D_; ++d)
        cm = fmaxf(cm, out[base + (size_t)d * HW_]);
    #pragma unroll 8
    for (int d = 0; d < D_; ++d) {
        size_t idx = base + (size_t)d * HW_;
        float v = out[idx];
        if (v == 0.0f) out[idx] = cm;
    }
}

// ---------------------------------------------------------------------------
extern "C" void kernel_launch(void* const* d_in, const int* in_sizes, int n_in,
                              void* d_out, int out_size, void* d_ws, size_t ws_size,
                              hipStream_t stream) {
    const float* cur        = (const float*)d_in[0];  // [B,C,H,W]
    const float* lf         = (const float*)d_in[1];  // [B,F,C,H,W]
    const float* poses      = (const float*)d_in[2];  // [B,F,4,4]
    const float* K          = (const float*)d_in[3];  // [B,4,4]
    const float* invK       = (const float*)d_in[4];  // [B,4,4]
    const float* depth_bins = (const float*)d_in[5];  // [D]
    float* out = (float*)d_out;
    float* ws  = (float*)d_ws;

    prep_kernel<<<NT_BLKS, 256, 0, stream>>>(cur, lf, ws);
    mega_kernel<<<B_ * H_ * 2 * XT_, 256, 0, stream>>>(poses, K, invK, depth_bins, ws, out);
    fixup_kernel<<<B_ * H_, 128, 0, stream>>>(out);
}

// Round 5
// 118.498 us; speedup vs baseline: 1.1217x; 1.1217x over previous
//
#include <hip/hip_runtime.h>
#include <math.h>

// Problem constants: B,F,C,H,W,D
constexpr int B_ = 2, F_ = 2, C_ = 64, H_ = 32, W_ = 104, D_ = 96;
constexpr int HW_ = H_ * W_;             // 3328
#define EPSF 1e-7f

// Workspace layout:
//   lfT  [B,F,H,W,C]  bf16 (ushort)  channel-last lookup feats  -- R12: bf16 halves L2 corner traffic
//   curT [B,H,W,C]    f32            channel-last current feats
constexpr size_t LFT_ELEMS  = (size_t)B_ * F_ * HW_ * C_;   // 851968 ushorts = 1,703,936 B
constexpr size_t CURT_OFF_F = LFT_ELEMS / 2;                // 425984 floats (byte offset identical)

constexpr int NT_BLKS = (HW_ / 32) * (C_ / 32) * (B_ * F_ + B_);  // 1248
constexpr int PXB   = 4;        // pixels per block — 16B stores + reuse sweet spot (R10: PXB=2 => 9x write amp)
constexpr int XT_   = W_ / PXB; // 26 x-tiles
// R14: depth-split — each block covers 48 of 96 depths; 2x blocks for tail fill.
// R13 lesson: conditional-def register pipelines -> local mem (+42MB WRITE).
// R14 lesson: __launch_bounds__(256,8) caps VGPR at 64 -> allocator hit 32 ->
//   spill (+20MB WRITE). R15: (256,4) = no register pressure; 8 blocks/CU comes
//   from the HARDWARE limit (VGPR<=64, LDS 8KB) instead of a forced squeeze.
constexpr int DL_   = 48;       // depths per block
constexpr int DPAD  = DL_ + 1;  // 49: float4 row stride
constexpr int DPADI = DL_ + 4;  // 52: int row stride (multiple of 4 -> int4 rows 16B aligned)

// DPP butterfly add over 16-lane group — bit-identical to __shfl_xor chain
// (only commutes IEEE add operands). VALU-only: no ds_swizzle latency.
template<int CTRL>
__device__ __forceinline__ float dpp_add(float x) {
    int y = __builtin_amdgcn_update_dpp(0, __float_as_int(x), CTRL, 0xf, 0xf, true);
    return x + __int_as_float(y);
}
__device__ __forceinline__ float group16_sum(float s) {
    s = dpp_add<0xB1>(s);    // quad_perm(1,0,3,2)  == + lane^1
    s = dpp_add<0x4E>(s);    // quad_perm(2,3,0,1)  == + lane^2
    s = dpp_add<0x141>(s);   // row_half_mirror     == + lane^4-equiv
    s = dpp_add<0x140>(s);   // row_mirror          == + lane^8-equiv
    return s;
}

// f32 -> bf16 with round-to-nearest-even (features are finite; no NaN path needed)
__device__ __forceinline__ ushort f2bf(float f) {
    unsigned u = __float_as_uint(f);
    u += 0x7FFFu + ((u >> 16) & 1u);
    return (ushort)(u >> 16);
}
// unpack 4 consecutive bf16 channels (one uint2) to float4
__device__ __forceinline__ float4 bf4(uint2 q) {
    return make_float4(__uint_as_float(q.x << 16),
                       __uint_as_float(q.x & 0xffff0000u),
                       __uint_as_float(q.y << 16),
                       __uint_as_float(q.y & 0xffff0000u));
}

// ---------------------------------------------------------------------------
// Prep: channel-last transpose [C, HW] -> [HW, C] for 6 slices.
// lf slices (0..3) are written as bf16; cur slices (4..5) stay f32.
__global__ __launch_bounds__(256) void prep_kernel(
        const float* __restrict__ cur, const float* __restrict__ lf,
        float* __restrict__ ws) {
    __shared__ float tile[32][33];
    int bid = blockIdx.x;
    int slice = bid / 208;            // 208 = 104 n-blocks * 2 c-blocks
    int rem   = bid % 208;
    int nb = rem % 104, cb = rem / 104;
    const float* inS = (slice < B_ * F_)
        ? lf  + (size_t)slice * C_ * HW_
        : cur + (size_t)(slice - B_ * F_) * C_ * HW_;
    int t = threadIdx.x;
    int tx = t & 31, ty = t >> 5;
    int n0 = nb * 32, c0 = cb * 32;
    #pragma unroll
    for (int k = 0; k < 32; k += 8)
        tile[ty + k][tx] = inS[(size_t)(c0 + ty + k) * HW_ + n0 + tx];
    __syncthreads();
    if (slice < B_ * F_) {
        ushort* outS = (ushort*)ws + (size_t)slice * HW_ * C_;
        #pragma unroll
        for (int k = 0; k < 32; k += 8)
            outS[(size_t)(n0 + ty + k) * C_ + c0 + tx] = f2bf(tile[tx][ty + k]);
    } else {
        float* outS = ws + CURT_OFF_F + (size_t)(slice - B_ * F_) * HW_ * C_;
        #pragma unroll
        for (int k = 0; k < 32; k += 8)
            outS[(size_t)(n0 + ty + k) * C_ + c0 + tx] = tile[tx][ty + k];
    }
}

// ---------------------------------------------------------------------------
// Mega kernel (R15): block = (b, y, xt, dhalf) covering 4 px * 48 depths * 2
// frames. 256 threads = 4 quarters x (16 lanes x 4 px); each quarter walks 12
// depths. Phase A: 192 projections -> LDS {offset, float4 weights} (bit-
// identical FP op order — mask-critical, do not touch). Phase B: R12-form
// consume-time deduped bf16 corner loads + DPP channel reduce; cost stored
// RAW (zeros kept) straight to out. Missing-fill moved to fixup_kernel.
__global__ __launch_bounds__(256, 4) void mega_kernel(
        const float* __restrict__ poses, const float* __restrict__ K,
        const float* __restrict__ invK, const float* __restrict__ depth_bins,
        const float* __restrict__ ws, float* __restrict__ out) {
    int t   = threadIdx.x;
    int bid = blockIdx.x;
    int xt  = bid % XT_;  int r = bid / XT_;
    int dhalf = r & 1;    r >>= 1;      // adjacent bids share (b,y,xt) -> L2 locality
    int y   = r % H_;
    int b   = r / H_;
    int d0g = dhalf * DL_;              // global depth base of this block

    if (y < 2 || y >= H_ - 2) {
        // whole row masked: cost 0 everywhere; fixup max over column = 0 -> stays 0
        for (int k = t; k < PXB * DL_; k += 256) {
            int d = d0g + (k >> 2), px = k & 3;
            out[((size_t)(b * D_ + d) * H_ + y) * W_ + xt * PXB + px] = 0.0f;
        }
        return;   // block-uniform exit
    }

    __shared__ alignas(16) int offsL[F_][PXB][DPADI];
    __shared__ float4 wtsL [F_][PXB][DPAD];

    // ---- Phase A: projections (FP op order identical to R9/R11) ----
    {
        // px = t & 3 — invariant. Hoist cam/interior.
        int pxA = t & 3;
        int xA  = xt * PXB + pxA;
        const float* iK = invK + (size_t)b * 16;
        float xf = (float)xA, yf = (float)y;
        float cam0 = __fmul_rn(iK[0], xf); cam0 = __fmaf_rn(iK[1], yf, cam0); cam0 = __fmaf_rn(iK[2],  1.0f, cam0);
        float cam1 = __fmul_rn(iK[4], xf); cam1 = __fmaf_rn(iK[5], yf, cam1); cam1 = __fmaf_rn(iK[6],  1.0f, cam1);
        float cam2 = __fmul_rn(iK[8], xf); cam2 = __fmaf_rn(iK[9], yf, cam2); cam2 = __fmaf_rn(iK[10], 1.0f, cam2);
        bool interior = (xA >= 2) && (xA <= W_ - 3);   // y already interior

        #pragma unroll
        for (int f = 0; f < F_; ++f) {
            const float* Kb   = K + (size_t)b * 16;
            const float* pose = poses + (size_t)(b * F_ + f) * 16;
            float P[12];
            #pragma unroll
            for (int i = 0; i < 3; ++i) {
                #pragma unroll
                for (int k = 0; k < 4; ++k) {
                    float acc = __fmul_rn(Kb[i*4+0], pose[0*4+k]);
                    acc = __fmaf_rn(Kb[i*4+1], pose[1*4+k], acc);
                    acc = __fmaf_rn(Kb[i*4+2], pose[2*4+k], acc);
                    acc = __fmaf_rn(Kb[i*4+3], pose[3*4+k], acc);
                    P[i*4+k] = acc;
                }
            }
            float vs = 0.f;
            #pragma unroll
            for (int j = 0; j < 16; ++j) vs += pose[j];
            bool valid = (vs != 0.f);

            // 192 records = dd*4 + px, single pass (threads 192..255 idle)
            if (t < PXB * DL_) {
                int dd = t >> 2;                       // local depth
                float depth = depth_bins[d0g + dd];
                float p0 = __fmul_rn(depth, cam0);
                float p1 = __fmul_rn(depth, cam1);
                float p2 = __fmul_rn(depth, cam2);
                float c0 = __fmul_rn(P[0], p0); c0 = __fmaf_rn(P[1], p1, c0); c0 = __fmaf_rn(P[2],  p2, c0); c0 = __fmaf_rn(P[3],  1.0f, c0);
                float c1 = __fmul_rn(P[4], p0); c1 = __fmaf_rn(P[5], p1, c1); c1 = __fmaf_rn(P[6],  p2, c1); c1 = __fmaf_rn(P[7],  1.0f, c1);
                float c2 = __fmul_rn(P[8], p0); c2 = __fmaf_rn(P[9], p1, c2); c2 = __fmaf_rn(P[10], p2, c2); c2 = __fmaf_rn(P[11], 1.0f, c2);
                float denom = __fadd_rn(c2, EPSF);
                float gx = c0 / denom;   // IEEE div — mask-critical
                float gy = c1 / denom;
                bool m = valid && interior && (gx >= 2.0f) && (gx <= (float)(W_ - 2))
                                           && (gy >= 2.0f) && (gy <= (float)(H_ - 2));
                if (m) {
                    float x0f = floorf(gx), y0f = floorf(gy);
                    int   x0  = (int)x0f,   y0  = (int)y0f;
                    float wx1 = gx - x0f, wy1 = gy - y0f;
                    float wx0 = 1.f - wx1, wy0 = 1.f - wy1;
                    wtsL[f][pxA][dd] = make_float4(wy0 * wx0, wy0 * wx1,
                                                   wy1 * wx0, wy1 * wx1);
                    offsL[f][pxA][dd] = (y0 * W_ + x0) * C_;   // element offset (ushort units)
                } else {
                    offsL[f][pxA][dd] = -1;
                    // NaN-safety: weights MUST be finite (diff = s*0; 0*NaN=NaN).
                    wtsL[f][pxA][dd] = make_float4(0.f, 0.f, 0.f, 0.f);
                }
            }
        }
    }
    __syncthreads();

    // ---- Phase B: deduped bf16 corner loads + DPP channel reduce (R12 form) ----
    {
        int lane = t & 15, px = (t >> 4) & 3, quarter = t >> 6;  // quarter in [0,4)
        int x = xt * PXB + px;
        const float4 cv = *(const float4*)(ws + CURT_OFF_F
                            + ((size_t)((b * H_ + y) * W_ + x)) * C_ + lane * 4);
        // two bases per frame: row y0 and row y0+1 (col x0+1 is +C_ = 128B imm)
        const ushort* lfbase = (const ushort*)ws;
        const ushort* lf0a = lfbase + (size_t)(b * F_ + 0) * HW_ * C_ + lane * 4;
        const ushort* lf0b = lf0a + W_ * C_;
        const ushort* lf1a = lfbase + (size_t)(b * F_ + 1) * HW_ * C_ + lane * 4;
        const ushort* lf1b = lf1a + W_ * C_;

        float4 cc0[4], cc1[4];
        int oprev0 = -1, oprev1 = -1;
        #pragma unroll
        for (int k = 0; k < 4; ++k)
            cc0[k] = cc1[k] = make_float4(0.f, 0.f, 0.f, 0.f);

        size_t outbase = ((size_t)(b * D_ + d0g) * H_ + y) * W_ + x;
        int dbeg = quarter * (DL_ / 4);                  // 12 depths per quarter
        for (int ki4 = 0; ki4 < DL_ / 16; ++ki4) {       // 3 groups of 4 depths
            int dc4 = dbeg + ki4 * 4;
            int4 oq0 = *(const int4*)&offsL[0][px][dc4]; // one ds_read_b128 / frame / 4 depths
            int4 oq1 = *(const int4*)&offsL[1][px][dc4];
            int oa0[4] = {oq0.x, oq0.y, oq0.z, oq0.w};   // static-indexed (unrolled j)
            int oa1[4] = {oq1.x, oq1.y, oq1.z, oq1.w};

            #pragma unroll
            for (int j = 0; j < 4; ++j) {
                int dc = dc4 + j;
                int    oc0 = oa0[j],          oc1 = oa1[j];
                float4 wc0 = wtsL[0][px][dc], wc1 = wtsL[1][px][dc];

                float costsum = 0.f, counts = 0.f;
                // f = 0
                {
                    bool m = (oc0 >= 0);
                    if (m && oc0 != oprev0) {     // 16-lane-group-uniform branch
                        cc0[0] = bf4(*(const uint2*)(lf0a + oc0));
                        cc0[1] = bf4(*(const uint2*)(lf0a + oc0 + C_));
                        cc0[2] = bf4(*(const uint2*)(lf0b + oc0));
                        cc0[3] = bf4(*(const uint2*)(lf0b + oc0 + C_));
                        oprev0 = oc0;
                    }
                    float a0 = __fmaf_rn(cc0[0].x, wc0.x, __fmaf_rn(cc0[1].x, wc0.y, __fmaf_rn(cc0[2].x, wc0.z, __fmaf_rn(cc0[3].x, wc0.w, -cv.x))));
                    float a1 = __fmaf_rn(cc0[0].y, wc0.x, __fmaf_rn(cc0[1].y, wc0.y, __fmaf_rn(cc0[2].y, wc0.z, __fmaf_rn(cc0[3].y, wc0.w, -cv.y))));
                    float a2 = __fmaf_rn(cc0[0].z, wc0.x, __fmaf_rn(cc0[1].z, wc0.y, __fmaf_rn(cc0[2].z, wc0.z, __fmaf_rn(cc0[3].z, wc0.w, -cv.z))));
                    float a3 = __fmaf_rn(cc0[0].w, wc0.x, __fmaf_rn(cc0[1].w, wc0.y, __fmaf_rn(cc0[2].w, wc0.z, __fmaf_rn(cc0[3].w, wc0.w, -cv.w))));
                    float s = (fabsf(a0) + fabsf(a1)) + (fabsf(a2) + fabsf(a3));
                    s = group16_sum(s);
                    float diff = __fmul_rn(s, 1.0f / 64.0f) * (m ? 1.0f : 0.0f);
                    costsum += diff;
                    counts  += (diff > 0.f) ? 1.0f : 0.0f;
                }
                // f = 1
                {
                    bool m = (oc1 >= 0);
                    if (m && oc1 != oprev1) {
                        cc1[0] = bf4(*(const uint2*)(lf1a + oc1));
                        cc1[1] = bf4(*(const uint2*)(lf1a + oc1 + C_));
                        cc1[2] = bf4(*(const uint2*)(lf1b + oc1));
                        cc1[3] = bf4(*(const uint2*)(lf1b + oc1 + C_));
                        oprev1 = oc1;
                    }
                    float a0 = __fmaf_rn(cc1[0].x, wc1.x, __fmaf_rn(cc1[1].x, wc1.y, __fmaf_rn(cc1[2].x, wc1.z, __fmaf_rn(cc1[3].x, wc1.w, -cv.x))));
                    float a1 = __fmaf_rn(cc1[0].y, wc1.x, __fmaf_rn(cc1[1].y, wc1.y, __fmaf_rn(cc1[2].y, wc1.z, __fmaf_rn(cc1[3].y, wc1.w, -cv.y))));
                    float a2 = __fmaf_rn(cc1[0].z, wc1.x, __fmaf_rn(cc1[1].z, wc1.y, __fmaf_rn(cc1[2].z, wc1.z, __fmaf_rn(cc1[3].z, wc1.w, -cv.z))));
                    float a3 = __fmaf_rn(cc1[0].w, wc1.x, __fmaf_rn(cc1[1].w, wc1.y, __fmaf_rn(cc1[2].w, wc1.z, __fmaf_rn(cc1[3].w, wc1.w, -cv.w))));
                    float s = (fabsf(a0) + fabsf(a1)) + (fabsf(a2) + fabsf(a3));
                    s = group16_sum(s);
                    float diff = __fmul_rn(s, 1.0f / 64.0f) * (m ? 1.0f : 0.0f);
                    costsum += diff;
                    counts  += (diff > 0.f) ? 1.0f : 0.0f;
                }
                // cost via fast rcp: ~1e-7 rel err (bf16 threshold 2.9e-2), and
                // EXACT zero preserved (costsum==0 -> 0*rcp(eps)=0) so the ==0.0
                // missing-fill semantics are unchanged.
                float cost = costsum * __builtin_amdgcn_rcpf(__fadd_rn(counts, EPSF));
                // raw store (zeros kept); 4 px-group lane0s of a wave store
                // consecutive x -> one 16B segment per wave-store.
                if (lane == 0) out[outbase + (size_t)dc * HW_] = cost;
            }
        }
    }
}

// ---------------------------------------------------------------------------
// Fixup: per (b,y,x) column over d — cmax = max(cost), cost==0 -> cmax.
// Exact-max, order-free; ==0.0 semantics identical to in-block Phase C.
// Tiny: 5 MB L2-hot traffic, runs after mega on the same stream.
__global__ __launch_bounds__(128) void fixup_kernel(float* __restrict__ out) {
    int by = blockIdx.x;            // [0, B*H)
    int b = by / H_, y = by % H_;
    int x = threadIdx.x;
    if (x >= W_) return;
    size_t base = ((size_t)(b * D_) * H_ + y) * W_ + x;
    float cm = 0.f;
    #pragma unroll 8
    for (int d = 0; d < D_; ++d)
        cm = fmaxf(cm, out[base + (size_t)d * HW_]);
    #pragma unroll 8
    for (int d = 0; d < D_; ++d) {
        size_t idx = base + (size_t)d * HW_;
        float v = out[idx];
        if (v == 0.0f) out[idx] = cm;
    }
}

// ---------------------------------------------------------------------------
extern "C" void kernel_launch(void* const* d_in, const int* in_sizes, int n_in,
                              void* d_out, int out_size, void* d_ws, size_t ws_size,
                              hipStream_t stream) {
    const float* cur        = (const float*)d_in[0];  // [B,C,H,W]
    const float* lf         = (const float*)d_in[1];  // [B,F,C,H,W]
    const float* poses      = (const float*)d_in[2];  // [B,F,4,4]
    const float* K          = (const float*)d_in[3];  // [B,4,4]
    const float* invK       = (const float*)d_in[4];  // [B,4,4]
    const float* depth_bins = (const float*)d_in[5];  // [D]
    float* out = (float*)d_out;
    float* ws  = (float*)d_ws;

    prep_kernel<<<NT_BLKS, 256, 0, stream>>>(cur, lf, ws);
    mega_kernel<<<B_ * H_ * 2 * XT_, 256, 0, stream>>>(poses, K, invK, depth_bins, ws, out);
    fixup_kernel<<<B_ * H_, 128, 0, stream>>>(out);
}

// Round 6
// 106.211 us; speedup vs baseline: 1.2515x; 1.1157x over previous
//
#include <hip/hip_runtime.h>
#include <math.h>

// Problem constants: B,F,C,H,W,D
constexpr int B_ = 2, F_ = 2, C_ = 64, H_ = 32, W_ = 104, D_ = 96;
constexpr int HW_ = H_ * W_;             // 3328
#define EPSF 1e-7f

// Workspace layout:
//   lfT  [B,F,H,W,C]  bf16 (ushort)  channel-last lookup feats  -- R12: bf16 halves corner bytes
//   curT [B,H,W,C]    f32            channel-last current feats
constexpr size_t LFT_ELEMS  = (size_t)B_ * F_ * HW_ * C_;   // 851968 ushorts = 1,703,936 B
constexpr size_t CURT_OFF_F = LFT_ELEMS / 2;                // 425984 floats (byte offset identical)

constexpr int NT_BLKS = (HW_ / 32) * (C_ / 32) * (B_ * F_ + B_);  // 1248
constexpr int PXB   = 4;        // pixels per block — 16B stores + reuse sweet spot
constexpr int XT_   = W_ / PXB; // 26 x-tiles
constexpr int DPAD  = D_ + 1;   // 97: float4 row stride
constexpr int DPADI = D_ + 4;   // 100: int row stride (multiple of 4 -> int4 rows 16B aligned)

// Lesson ledger:
//  R13: conditional-def register pipeline -> local-mem demotion (+42MB WRITE). Never.
//  R14: __launch_bounds__(256,8) VGPR cap 64 -> spill (+20MB WRITE). Never squeeze.
//  R15: occupancy released, mega unchanged ~41µs -> occupancy is a dead lever.
//  R16: the dedup BRANCH was the pipeline blocker. Loads now unconditional
//       (masked -> safe offset 0, weights 0 kill the value) so the compiler
//       can hoist loads across depths with counted vmcnt. Redundant loads
//       hit L1 (working set ~1.3KB/group).

// DPP butterfly add over 16-lane group — bit-identical to __shfl_xor chain
// (only commutes IEEE add operands). VALU-only: no ds_swizzle latency.
template<int CTRL>
__device__ __forceinline__ float dpp_add(float x) {
    int y = __builtin_amdgcn_update_dpp(0, __float_as_int(x), CTRL, 0xf, 0xf, true);
    return x + __int_as_float(y);
}
__device__ __forceinline__ float group16_sum(float s) {
    s = dpp_add<0xB1>(s);    // quad_perm(1,0,3,2)  == + lane^1
    s = dpp_add<0x4E>(s);    // quad_perm(2,3,0,1)  == + lane^2
    s = dpp_add<0x141>(s);   // row_half_mirror     == + lane^4-equiv
    s = dpp_add<0x140>(s);   // row_mirror          == + lane^8-equiv
    return s;
}

// f32 -> bf16 with round-to-nearest-even (features are finite; no NaN path needed)
__device__ __forceinline__ ushort f2bf(float f) {
    unsigned u = __float_as_uint(f);
    u += 0x7FFFu + ((u >> 16) & 1u);
    return (ushort)(u >> 16);
}
// unpack 4 consecutive bf16 channels (one uint2) to float4
__device__ __forceinline__ float4 bf4(uint2 q) {
    return make_float4(__uint_as_float(q.x << 16),
                       __uint_as_float(q.x & 0xffff0000u),
                       __uint_as_float(q.y << 16),
                       __uint_as_float(q.y & 0xffff0000u));
}

// ---------------------------------------------------------------------------
// Prep: channel-last transpose [C, HW] -> [HW, C] for 6 slices.
// lf slices (0..3) are written as bf16; cur slices (4..5) stay f32.
__global__ __launch_bounds__(256) void prep_kernel(
        const float* __restrict__ cur, const float* __restrict__ lf,
        float* __restrict__ ws) {
    __shared__ float tile[32][33];
    int bid = blockIdx.x;
    int slice = bid / 208;            // 208 = 104 n-blocks * 2 c-blocks
    int rem   = bid % 208;
    int nb = rem % 104, cb = rem / 104;
    const float* inS = (slice < B_ * F_)
        ? lf  + (size_t)slice * C_ * HW_
        : cur + (size_t)(slice - B_ * F_) * C_ * HW_;
    int t = threadIdx.x;
    int tx = t & 31, ty = t >> 5;
    int n0 = nb * 32, c0 = cb * 32;
    #pragma unroll
    for (int k = 0; k < 32; k += 8)
        tile[ty + k][tx] = inS[(size_t)(c0 + ty + k) * HW_ + n0 + tx];
    __syncthreads();
    if (slice < B_ * F_) {
        ushort* outS = (ushort*)ws + (size_t)slice * HW_ * C_;
        #pragma unroll
        for (int k = 0; k < 32; k += 8)
            outS[(size_t)(n0 + ty + k) * C_ + c0 + tx] = f2bf(tile[tx][ty + k]);
    } else {
        float* outS = ws + CURT_OFF_F + (size_t)(slice - B_ * F_) * HW_ * C_;
        #pragma unroll
        for (int k = 0; k < 32; k += 8)
            outS[(size_t)(n0 + ty + k) * C_ + c0 + tx] = tile[tx][ty + k];
    }
}

// ---------------------------------------------------------------------------
// Mega kernel (R16): block = (b, y, xt) covering 4 px * ALL 96 depths * 2
// frames. 256 threads = 4 halves x (16 lanes x 4 px); each half walks 24
// depths. Phase A: 768 projections -> LDS {offset, float4 weights} (bit-
// identical FP op order — mask-critical, do not touch). Phase B: branchless
// corner loads in pairs-of-depths (16 loads in flight), bf16 unpack, fma
// chain folding -cv, DPP channel reduce, v_rcp cost. Phase C: in-block
// missing-fill (cost==0 -> column max) + store.
__global__ __launch_bounds__(256, 4) void mega_kernel(
        const float* __restrict__ poses, const float* __restrict__ K,
        const float* __restrict__ invK, const float* __restrict__ depth_bins,
        const float* __restrict__ ws, float* __restrict__ out) {
    int t   = threadIdx.x;
    int bid = blockIdx.x;
    int xt  = bid % XT_;  int r = bid / XT_;
    int y   = r % H_;
    int b   = r / H_;

    if (y < 2 || y >= H_ - 2) {
        // whole row masked: cost column all-zero -> column max 0 -> output 0
        for (int k = t; k < PXB * D_; k += 256) {
            int d = k >> 2, px = k & 3;
            out[((size_t)(b * D_ + d) * H_ + y) * W_ + xt * PXB + px] = 0.0f;
        }
        return;   // block-uniform exit
    }

    __shared__ alignas(16) int offsL[F_][PXB][DPADI];
    __shared__ float4 wtsL [F_][PXB][DPAD];
    __shared__ float  costb[PXB][DPAD];
    __shared__ float  pmax[32][PXB];
    __shared__ float  cmaxb[PXB];

    // ---- Phase A: projections (FP op order identical to R9/R11) ----
    {
        // px = (t + 256k) & 3 = t & 3 — invariant across k. Hoist cam/interior.
        int pxA = t & 3;
        int xA  = xt * PXB + pxA;
        const float* iK = invK + (size_t)b * 16;
        float xf = (float)xA, yf = (float)y;
        float cam0 = __fmul_rn(iK[0], xf); cam0 = __fmaf_rn(iK[1], yf, cam0); cam0 = __fmaf_rn(iK[2],  1.0f, cam0);
        float cam1 = __fmul_rn(iK[4], xf); cam1 = __fmaf_rn(iK[5], yf, cam1); cam1 = __fmaf_rn(iK[6],  1.0f, cam1);
        float cam2 = __fmul_rn(iK[8], xf); cam2 = __fmaf_rn(iK[9], yf, cam2); cam2 = __fmaf_rn(iK[10], 1.0f, cam2);
        bool interior = (xA >= 2) && (xA <= W_ - 3);   // y already interior

        #pragma unroll
        for (int f = 0; f < F_; ++f) {
            const float* Kb   = K + (size_t)b * 16;
            const float* pose = poses + (size_t)(b * F_ + f) * 16;
            float P[12];
            #pragma unroll
            for (int i = 0; i < 3; ++i) {
                #pragma unroll
                for (int k = 0; k < 4; ++k) {
                    float acc = __fmul_rn(Kb[i*4+0], pose[0*4+k]);
                    acc = __fmaf_rn(Kb[i*4+1], pose[1*4+k], acc);
                    acc = __fmaf_rn(Kb[i*4+2], pose[2*4+k], acc);
                    acc = __fmaf_rn(Kb[i*4+3], pose[3*4+k], acc);
                    P[i*4+k] = acc;
                }
            }
            float vs = 0.f;
            #pragma unroll
            for (int j = 0; j < 16; ++j) vs += pose[j];
            bool valid = (vs != 0.f);

            #pragma unroll
            for (int k = 0; k < 2; ++k) {
                int idx = t + 256 * k;          // records [0,384) = dd*4 + px
                if (idx < PXB * D_) {
                    int dd = idx >> 2;
                    float depth = depth_bins[dd];
                    float p0 = __fmul_rn(depth, cam0);
                    float p1 = __fmul_rn(depth, cam1);
                    float p2 = __fmul_rn(depth, cam2);
                    float c0 = __fmul_rn(P[0], p0); c0 = __fmaf_rn(P[1], p1, c0); c0 = __fmaf_rn(P[2],  p2, c0); c0 = __fmaf_rn(P[3],  1.0f, c0);
                    float c1 = __fmul_rn(P[4], p0); c1 = __fmaf_rn(P[5], p1, c1); c1 = __fmaf_rn(P[6],  p2, c1); c1 = __fmaf_rn(P[7],  1.0f, c1);
                    float c2 = __fmul_rn(P[8], p0); c2 = __fmaf_rn(P[9], p1, c2); c2 = __fmaf_rn(P[10], p2, c2); c2 = __fmaf_rn(P[11], 1.0f, c2);
                    float denom = __fadd_rn(c2, EPSF);
                    float gx = c0 / denom;   // IEEE div — mask-critical
                    float gy = c1 / denom;
                    bool m = valid && interior && (gx >= 2.0f) && (gx <= (float)(W_ - 2))
                                               && (gy >= 2.0f) && (gy <= (float)(H_ - 2));
                    if (m) {
                        float x0f = floorf(gx), y0f = floorf(gy);
                        int   x0  = (int)x0f,   y0  = (int)y0f;
                        float wx1 = gx - x0f, wy1 = gy - y0f;
                        float wx0 = 1.f - wx1, wy0 = 1.f - wy1;
                        wtsL[f][pxA][dd] = make_float4(wy0 * wx0, wy0 * wx1,
                                                       wy1 * wx0, wy1 * wx1);
                        offsL[f][pxA][dd] = (y0 * W_ + x0) * C_;   // element offset (ushort units)
                    } else {
                        offsL[f][pxA][dd] = -1;
                        // NaN-safety: weights MUST be finite (diff = s*0; 0*NaN=NaN).
                        wtsL[f][pxA][dd] = make_float4(0.f, 0.f, 0.f, 0.f);
                    }
                }
            }
        }
    }
    __syncthreads();

    // ---- Phase B: branchless pipelined bf16 corner loads + DPP reduce ----
    {
        int lane = t & 15, px = (t >> 4) & 3, half = t >> 6;  // half in [0,4)
        int x = xt * PXB + px;
        const float4 cv = *(const float4*)(ws + CURT_OFF_F
                            + ((size_t)((b * H_ + y) * W_ + x)) * C_ + lane * 4);
        // two bases per frame: row y0 and row y0+1 (col x0+1 is +C_ = 128B imm)
        const ushort* lfbase = (const ushort*)ws;
        const ushort* lf0a = lfbase + (size_t)(b * F_ + 0) * HW_ * C_ + lane * 4;
        const ushort* lf0b = lf0a + W_ * C_;
        const ushort* lf1a = lfbase + (size_t)(b * F_ + 1) * HW_ * C_ + lane * 4;
        const ushort* lf1b = lf1a + W_ * C_;

        int dbeg = half * (D_ / 4);
        for (int ki4 = 0; ki4 < D_ / 16; ++ki4) {     // 6 groups of 4 depths
            int dc4 = dbeg + ki4 * 4;
            int4 oq0 = *(const int4*)&offsL[0][px][dc4];   // one ds_read_b128 / frame / 4 depths
            int4 oq1 = *(const int4*)&offsL[1][px][dc4];
            int oa0[4] = {oq0.x, oq0.y, oq0.z, oq0.w};     // static-indexed (unrolled below)
            int oa1[4] = {oq1.x, oq1.y, oq1.z, oq1.w};

            #pragma unroll
            for (int jp = 0; jp < 2; ++jp) {          // pairs: 16 loads, then 2 computes
                // q[] is statically indexed and UNCONDITIONALLY written (R13
                // lesson: conditional defs demote to scratch).
                uint2 q[2][8];
                #pragma unroll
                for (int u = 0; u < 2; ++u) {
                    int j = jp * 2 + u;
                    int oc0 = oa0[j], oc1 = oa1[j];
                    int os0 = oc0 & ~(oc0 >> 31);     // max(oc,0): masked -> slice start (safe,
                    int os1 = oc1 & ~(oc1 >> 31);     // finite data; weights 0 kill the value)
                    q[u][0] = *(const uint2*)(lf0a + os0);
                    q[u][1] = *(const uint2*)(lf0a + os0 + C_);
                    q[u][2] = *(const uint2*)(lf0b + os0);
                    q[u][3] = *(const uint2*)(lf0b + os0 + C_);
                    q[u][4] = *(const uint2*)(lf1a + os1);
                    q[u][5] = *(const uint2*)(lf1a + os1 + C_);
                    q[u][6] = *(const uint2*)(lf1b + os1);
                    q[u][7] = *(const uint2*)(lf1b + os1 + C_);
                }
                #pragma unroll
                for (int u = 0; u < 2; ++u) {
                    int j = jp * 2 + u;
                    int dc = dc4 + j;
                    float4 wc0 = wtsL[0][px][dc], wc1 = wtsL[1][px][dc];
                    bool m0 = (oa0[j] >= 0), m1 = (oa1[j] >= 0);
                    float4 c00 = bf4(q[u][0]), c01 = bf4(q[u][1]),
                           c02 = bf4(q[u][2]), c03 = bf4(q[u][3]);
                    float4 c10 = bf4(q[u][4]), c11 = bf4(q[u][5]),
                           c12 = bf4(q[u][6]), c13 = bf4(q[u][7]);

                    float costsum = 0.f, counts = 0.f;
                    // f = 0  (-cv folded into fma chain; masked: w=0 -> a=-cv,
                    //         killed by the m-multiply — FP order as R12)
                    {
                        float a0 = __fmaf_rn(c00.x, wc0.x, __fmaf_rn(c01.x, wc0.y, __fmaf_rn(c02.x, wc0.z, __fmaf_rn(c03.x, wc0.w, -cv.x))));
                        float a1 = __fmaf_rn(c00.y, wc0.x, __fmaf_rn(c01.y, wc0.y, __fmaf_rn(c02.y, wc0.z, __fmaf_rn(c03.y, wc0.w, -cv.y))));
                        float a2 = __fmaf_rn(c00.z, wc0.x, __fmaf_rn(c01.z, wc0.y, __fmaf_rn(c02.z, wc0.z, __fmaf_rn(c03.z, wc0.w, -cv.z))));
                        float a3 = __fmaf_rn(c00.w, wc0.x, __fmaf_rn(c01.w, wc0.y, __fmaf_rn(c02.w, wc0.z, __fmaf_rn(c03.w, wc0.w, -cv.w))));
                        float s = (fabsf(a0) + fabsf(a1)) + (fabsf(a2) + fabsf(a3));
                        s = group16_sum(s);
                        float diff = __fmul_rn(s, 1.0f / 64.0f) * (m0 ? 1.0f : 0.0f);
                        costsum += diff;
                        counts  += (diff > 0.f) ? 1.0f : 0.0f;
                    }
                    // f = 1
                    {
                        float a0 = __fmaf_rn(c10.x, wc1.x, __fmaf_rn(c11.x, wc1.y, __fmaf_rn(c12.x, wc1.z, __fmaf_rn(c13.x, wc1.w, -cv.x))));
                        float a1 = __fmaf_rn(c10.y, wc1.x, __fmaf_rn(c11.y, wc1.y, __fmaf_rn(c12.y, wc1.z, __fmaf_rn(c13.y, wc1.w, -cv.y))));
                        float a2 = __fmaf_rn(c10.z, wc1.x, __fmaf_rn(c11.z, wc1.y, __fmaf_rn(c12.z, wc1.z, __fmaf_rn(c13.z, wc1.w, -cv.z))));
                        float a3 = __fmaf_rn(c10.w, wc1.x, __fmaf_rn(c11.w, wc1.y, __fmaf_rn(c12.w, wc1.z, __fmaf_rn(c13.w, wc1.w, -cv.w))));
                        float s = (fabsf(a0) + fabsf(a1)) + (fabsf(a2) + fabsf(a3));
                        s = group16_sum(s);
                        float diff = __fmul_rn(s, 1.0f / 64.0f) * (m1 ? 1.0f : 0.0f);
                        costsum += diff;
                        counts  += (diff > 0.f) ? 1.0f : 0.0f;
                    }
                    // cost via fast rcp: ~1e-7 rel err (bf16 threshold 2.9e-2), and
                    // EXACT zero preserved (costsum==0 -> 0*rcp(eps)=0) so the ==0.0
                    // missing-fill semantics are unchanged.
                    float cost = costsum * __builtin_amdgcn_rcpf(__fadd_rn(counts, EPSF));
                    if (lane == 0) costb[px][dc] = cost;
                }
            }
        }
    }
    __syncthreads();

    // ---- Phase C: missing-fill + store (first 128 threads own the data) ----
    {
        int j = t >> 2, px = t & 3;          // j in [0,64); only j<32 used
        float v[3];
        if (t < 128) {
            float pm = 0.f;
            #pragma unroll
            for (int k = 0; k < 3; ++k) {
                v[k] = costb[px][j + 32 * k];
                pm = fmaxf(pm, v[k]);
            }
            pmax[j][px] = pm;
        }
        __syncthreads();
        if (t < PXB) {
            float cm = 0.f;
            #pragma unroll
            for (int jj = 0; jj < 32; ++jj) cm = fmaxf(cm, pmax[jj][t]);
            cmaxb[t] = cm;
        }
        __syncthreads();
        if (t < 128) {
            float cm = cmaxb[px];
            int x = xt * PXB + px;
            #pragma unroll
            for (int k = 0; k < 3; ++k) {
                int d = j + 32 * k;
                out[((size_t)(b * D_ + d) * H_ + y) * W_ + x] = (v[k] == 0.0f) ? cm : v[k];
            }
        }
    }
}

// ---------------------------------------------------------------------------
extern "C" void kernel_launch(void* const* d_in, const int* in_sizes, int n_in,
                              void* d_out, int out_size, void* d_ws, size_t ws_size,
                              hipStream_t stream) {
    const float* cur        = (const float*)d_in[0];  // [B,C,H,W]
    const float* lf         = (const float*)d_in[1];  // [B,F,C,H,W]
    const float* poses      = (const float*)d_in[2];  // [B,F,4,4]
    const float* K          = (const float*)d_in[3];  // [B,4,4]
    const float* invK       = (const float*)d_in[4];  // [B,4,4]
    const float* depth_bins = (const float*)d_in[5];  // [D]
    float* out = (float*)d_out;
    float* ws  = (float*)d_ws;

    prep_kernel<<<NT_BLKS, 256, 0, stream>>>(cur, lf, ws);
    mega_kernel<<<B_ * H_ * XT_, 256, 0, stream>>>(poses, K, invK, depth_bins, ws, out);
}

// Round 7
// 105.650 us; speedup vs baseline: 1.2581x; 1.0053x over previous
//
#include <hip/hip_runtime.h>
#include <math.h>

// Problem constants: B,F,C,H,W,D
constexpr int B_ = 2, F_ = 2, C_ = 64, H_ = 32, W_ = 104, D_ = 96;
constexpr int HW_ = H_ * W_;             // 3328
#define EPSF 1e-7f

// Workspace layout:
//   lfT  [B,F,H,W,C]  bf16 (ushort)  channel-last lookup feats  -- R12: bf16 halves corner bytes
//   curT [B,H,W,C]    f32            channel-last current feats
constexpr size_t LFT_ELEMS  = (size_t)B_ * F_ * HW_ * C_;   // 851968 ushorts = 1,703,936 B
constexpr size_t CURT_OFF_F = LFT_ELEMS / 2;                // 425984 floats (byte offset identical)

constexpr int NT_BLKS = (HW_ / 32) * (C_ / 32) * (B_ * F_ + B_);  // 1248
constexpr int PXB   = 4;        // pixels per block — 16B stores + reuse sweet spot
constexpr int XT_   = W_ / PXB; // 26 x-tiles
constexpr int DPAD  = D_ + 1;   // 97: row stride
constexpr int DPADI = D_ + 4;   // 100: int row stride (multiple of 4 -> int4 rows 16B aligned)

// Lesson ledger:
//  R13: conditional-def register pipeline -> local-mem demotion (+42MB WRITE). Never.
//  R14: __launch_bounds__(256,8) VGPR cap 64 -> spill (+20MB WRITE). Never squeeze.
//  R15: occupancy released, mega unchanged ~41µs -> occupancy is a dead lever.
//  R16: branchless loads removed the latency chain (FETCH 5.8MB, no spill) but
//       raised the VALU floor (unpack every depth): 46.6µs, VALU-bound.
//  R17: halve the math — v_perm packs (x0,x1) channel pairs, v_dot2_f32_bf16
//       does the bilinear blend (2 corners/inst) with -cv as the accumulator.
//       Weights packed bf16 in LDS (exact zeros for masked -> semantics kept).

// DPP butterfly add over 16-lane group — bit-identical to __shfl_xor chain
// (only commutes IEEE add operands). VALU-only: no ds_swizzle latency.
template<int CTRL>
__device__ __forceinline__ float dpp_add(float x) {
    int y = __builtin_amdgcn_update_dpp(0, __float_as_int(x), CTRL, 0xf, 0xf, true);
    return x + __int_as_float(y);
}
__device__ __forceinline__ float group16_sum(float s) {
    s = dpp_add<0xB1>(s);    // quad_perm(1,0,3,2)  == + lane^1
    s = dpp_add<0x4E>(s);    // quad_perm(2,3,0,1)  == + lane^2
    s = dpp_add<0x141>(s);   // row_half_mirror     == + lane^4-equiv
    s = dpp_add<0x140>(s);   // row_mirror          == + lane^8-equiv
    return s;
}

// f32 -> bf16 with round-to-nearest-even (weights/features finite; no NaN path)
__device__ __forceinline__ ushort f2bf(float f) {
    unsigned u = __float_as_uint(f);
    u += 0x7FFFu + ((u >> 16) & 1u);
    return (ushort)(u >> 16);
}

// v_dot2_f32_bf16: r = acc + a.lo*b.lo + a.hi*b.hi  (bf16x2 operands)
__device__ __forceinline__ float dot2bf(unsigned a, unsigned b, float acc) {
    float r;
    asm("v_dot2_f32_bf16 %0, %1, %2, %3" : "=v"(r) : "v"(a), "v"(b), "v"(acc));
    return r;
}

// ---------------------------------------------------------------------------
// Prep: channel-last transpose [C, HW] -> [HW, C] for 6 slices.
// lf slices (0..3) are written as bf16; cur slices (4..5) stay f32.
__global__ __launch_bounds__(256) void prep_kernel(
        const float* __restrict__ cur, const float* __restrict__ lf,
        float* __restrict__ ws) {
    __shared__ float tile[32][33];
    int bid = blockIdx.x;
    int slice = bid / 208;            // 208 = 104 n-blocks * 2 c-blocks
    int rem   = bid % 208;
    int nb = rem % 104, cb = rem / 104;
    const float* inS = (slice < B_ * F_)
        ? lf  + (size_t)slice * C_ * HW_
        : cur + (size_t)(slice - B_ * F_) * C_ * HW_;
    int t = threadIdx.x;
    int tx = t & 31, ty = t >> 5;
    int n0 = nb * 32, c0 = cb * 32;
    #pragma unroll
    for (int k = 0; k < 32; k += 8)
        tile[ty + k][tx] = inS[(size_t)(c0 + ty + k) * HW_ + n0 + tx];
    __syncthreads();
    if (slice < B_ * F_) {
        ushort* outS = (ushort*)ws + (size_t)slice * HW_ * C_;
        #pragma unroll
        for (int k = 0; k < 32; k += 8)
            outS[(size_t)(n0 + ty + k) * C_ + c0 + tx] = f2bf(tile[tx][ty + k]);
    } else {
        float* outS = ws + CURT_OFF_F + (size_t)(slice - B_ * F_) * HW_ * C_;
        #pragma unroll
        for (int k = 0; k < 32; k += 8)
            outS[(size_t)(n0 + ty + k) * C_ + c0 + tx] = tile[tx][ty + k];
    }
}

// ---------------------------------------------------------------------------
// Mega kernel (R17): block = (b, y, xt) covering 4 px * ALL 96 depths * 2
// frames. 256 threads = 4 halves x (16 lanes x 4 px); each half walks 24
// depths. Phase A: 768 projections -> LDS {offset, packed-bf16 weight pairs}
// (projection FP op order bit-identical — mask-critical, do not touch).
// Phase B: branchless corner loads in pairs-of-depths (16 loads in flight),
// v_perm channel-pair pack, v_dot2_f32_bf16 bilinear (acc starts at -cv),
// DPP channel reduce, v_rcp cost. Phase C: in-block missing-fill + store.
__global__ __launch_bounds__(256, 4) void mega_kernel(
        const float* __restrict__ poses, const float* __restrict__ K,
        const float* __restrict__ invK, const float* __restrict__ depth_bins,
        const float* __restrict__ ws, float* __restrict__ out) {
    int t   = threadIdx.x;
    int bid = blockIdx.x;
    int xt  = bid % XT_;  int r = bid / XT_;
    int y   = r % H_;
    int b   = r / H_;

    if (y < 2 || y >= H_ - 2) {
        // whole row masked: cost column all-zero -> column max 0 -> output 0
        for (int k = t; k < PXB * D_; k += 256) {
            int d = k >> 2, px = k & 3;
            out[((size_t)(b * D_ + d) * H_ + y) * W_ + xt * PXB + px] = 0.0f;
        }
        return;   // block-uniform exit
    }

    __shared__ alignas(16) int offsL[F_][PXB][DPADI];
    __shared__ alignas(16) uint2 wtsL[F_][PXB][DPAD];   // packed bf16 weight pairs
    __shared__ float  costb[PXB][DPAD];
    __shared__ float  pmax[32][PXB];
    __shared__ float  cmaxb[PXB];

    // ---- Phase A: projections (FP op order identical to R9/R11) ----
    {
        // px = (t + 256k) & 3 = t & 3 — invariant across k. Hoist cam/interior.
        int pxA = t & 3;
        int xA  = xt * PXB + pxA;
        const float* iK = invK + (size_t)b * 16;
        float xf = (float)xA, yf = (float)y;
        float cam0 = __fmul_rn(iK[0], xf); cam0 = __fmaf_rn(iK[1], yf, cam0); cam0 = __fmaf_rn(iK[2],  1.0f, cam0);
        float cam1 = __fmul_rn(iK[4], xf); cam1 = __fmaf_rn(iK[5], yf, cam1); cam1 = __fmaf_rn(iK[6],  1.0f, cam1);
        float cam2 = __fmul_rn(iK[8], xf); cam2 = __fmaf_rn(iK[9], yf, cam2); cam2 = __fmaf_rn(iK[10], 1.0f, cam2);
        bool interior = (xA >= 2) && (xA <= W_ - 3);   // y already interior

        #pragma unroll
        for (int f = 0; f < F_; ++f) {
            const float* Kb   = K + (size_t)b * 16;
            const float* pose = poses + (size_t)(b * F_ + f) * 16;
            float P[12];
            #pragma unroll
            for (int i = 0; i < 3; ++i) {
                #pragma unroll
                for (int k = 0; k < 4; ++k) {
                    float acc = __fmul_rn(Kb[i*4+0], pose[0*4+k]);
                    acc = __fmaf_rn(Kb[i*4+1], pose[1*4+k], acc);
                    acc = __fmaf_rn(Kb[i*4+2], pose[2*4+k], acc);
                    acc = __fmaf_rn(Kb[i*4+3], pose[3*4+k], acc);
                    P[i*4+k] = acc;
                }
            }
            float vs = 0.f;
            #pragma unroll
            for (int j = 0; j < 16; ++j) vs += pose[j];
            bool valid = (vs != 0.f);

            #pragma unroll
            for (int k = 0; k < 2; ++k) {
                int idx = t + 256 * k;          // records [0,384) = dd*4 + px
                if (idx < PXB * D_) {
                    int dd = idx >> 2;
                    float depth = depth_bins[dd];
                    float p0 = __fmul_rn(depth, cam0);
                    float p1 = __fmul_rn(depth, cam1);
                    float p2 = __fmul_rn(depth, cam2);
                    float c0 = __fmul_rn(P[0], p0); c0 = __fmaf_rn(P[1], p1, c0); c0 = __fmaf_rn(P[2],  p2, c0); c0 = __fmaf_rn(P[3],  1.0f, c0);
                    float c1 = __fmul_rn(P[4], p0); c1 = __fmaf_rn(P[5], p1, c1); c1 = __fmaf_rn(P[6],  p2, c1); c1 = __fmaf_rn(P[7],  1.0f, c1);
                    float c2 = __fmul_rn(P[8], p0); c2 = __fmaf_rn(P[9], p1, c2); c2 = __fmaf_rn(P[10], p2, c2); c2 = __fmaf_rn(P[11], 1.0f, c2);
                    float denom = __fadd_rn(c2, EPSF);
                    float gx = c0 / denom;   // IEEE div — mask-critical
                    float gy = c1 / denom;
                    bool m = valid && interior && (gx >= 2.0f) && (gx <= (float)(W_ - 2))
                                               && (gy >= 2.0f) && (gy <= (float)(H_ - 2));
                    if (m) {
                        float x0f = floorf(gx), y0f = floorf(gy);
                        int   x0  = (int)x0f,   y0  = (int)y0f;
                        float wx1 = gx - x0f, wy1 = gy - y0f;
                        float wx0 = 1.f - wx1, wy0 = 1.f - wy1;
                        // packed bf16 weight pairs: low bf16 = x0 weight
                        unsigned wlo = ((unsigned)f2bf(wy0 * wx1) << 16) | f2bf(wy0 * wx0);
                        unsigned whi = ((unsigned)f2bf(wy1 * wx1) << 16) | f2bf(wy1 * wx0);
                        wtsL[f][pxA][dd] = make_uint2(wlo, whi);
                        offsL[f][pxA][dd] = (y0 * W_ + x0) * C_;   // element offset (ushort units)
                    } else {
                        offsL[f][pxA][dd] = -1;
                        // exact bf16 zeros: finite corners * 0.0 = 0.0 -> a = -cv,
                        // killed by the m-multiply (semantics preserved).
                        wtsL[f][pxA][dd] = make_uint2(0u, 0u);
                    }
                }
            }
        }
    }
    __syncthreads();

    // ---- Phase B: branchless loads + perm/dot2 blend + DPP reduce ----
    {
        int lane = t & 15, px = (t >> 4) & 3, half = t >> 6;  // half in [0,4)
        int x = xt * PXB + px;
        const float4 cv = *(const float4*)(ws + CURT_OFF_F
                            + ((size_t)((b * H_ + y) * W_ + x)) * C_ + lane * 4);
        // two bases per frame: row y0 and row y0+1 (col x0+1 is +C_ = 256B imm)
        const ushort* lfbase = (const ushort*)ws;
        const ushort* lf0a = lfbase + (size_t)(b * F_ + 0) * HW_ * C_ + lane * 4;
        const ushort* lf0b = lf0a + W_ * C_;
        const ushort* lf1a = lfbase + (size_t)(b * F_ + 1) * HW_ * C_ + lane * 4;
        const ushort* lf1b = lf1a + W_ * C_;

        int dbeg = half * (D_ / 4);
        for (int ki4 = 0; ki4 < D_ / 16; ++ki4) {     // 6 groups of 4 depths
            int dc4 = dbeg + ki4 * 4;
            int4 oq0 = *(const int4*)&offsL[0][px][dc4];   // one ds_read_b128 / frame / 4 depths
            int4 oq1 = *(const int4*)&offsL[1][px][dc4];
            int oa0[4] = {oq0.x, oq0.y, oq0.z, oq0.w};     // static-indexed (unrolled below)
            int oa1[4] = {oq1.x, oq1.y, oq1.z, oq1.w};

            #pragma unroll
            for (int jp = 0; jp < 2; ++jp) {          // pairs: 16 loads, then 2 computes
                // q[] is statically indexed and UNCONDITIONALLY written (R13
                // lesson: conditional defs demote to scratch).
                uint2 q[2][8];
                #pragma unroll
                for (int u = 0; u < 2; ++u) {
                    int j = jp * 2 + u;
                    int oc0 = oa0[j], oc1 = oa1[j];
                    int os0 = oc0 & ~(oc0 >> 31);     // max(oc,0): masked -> slice start (safe,
                    int os1 = oc1 & ~(oc1 >> 31);     // finite data; zero weights kill the value)
                    q[u][0] = *(const uint2*)(lf0a + os0);        // row a, x0
                    q[u][1] = *(const uint2*)(lf0a + os0 + C_);   // row a, x1
                    q[u][2] = *(const uint2*)(lf0b + os0);        // row b, x0
                    q[u][3] = *(const uint2*)(lf0b + os0 + C_);   // row b, x1
                    q[u][4] = *(const uint2*)(lf1a + os1);
                    q[u][5] = *(const uint2*)(lf1a + os1 + C_);
                    q[u][6] = *(const uint2*)(lf1b + os1);
                    q[u][7] = *(const uint2*)(lf1b + os1 + C_);
                }
                #pragma unroll
                for (int u = 0; u < 2; ++u) {
                    int j = jp * 2 + u;
                    int dc = dc4 + j;
                    uint2 w0 = wtsL[0][px][dc], w1 = wtsL[1][px][dc];
                    bool m0 = (oa0[j] >= 0), m1 = (oa1[j] >= 0);

                    float costsum = 0.f, counts = 0.f;
                    // f = 0: v_perm packs (x0ch, x1ch) bf16 pairs; dot2 blends
                    // 2 corners/inst; row-a dot2 starts from -cv (fold the sub).
                    {
                        unsigned a0 = __builtin_amdgcn_perm(q[u][0].x, q[u][1].x, 0x01000504u);
                        unsigned a1 = __builtin_amdgcn_perm(q[u][0].x, q[u][1].x, 0x03020706u);
                        unsigned a2 = __builtin_amdgcn_perm(q[u][0].y, q[u][1].y, 0x01000504u);
                        unsigned a3 = __builtin_amdgcn_perm(q[u][0].y, q[u][1].y, 0x03020706u);
                        unsigned b0 = __builtin_amdgcn_perm(q[u][2].x, q[u][3].x, 0x01000504u);
                        unsigned b1 = __builtin_amdgcn_perm(q[u][2].x, q[u][3].x, 0x03020706u);
                        unsigned b2 = __builtin_amdgcn_perm(q[u][2].y, q[u][3].y, 0x01000504u);
                        unsigned b3 = __builtin_amdgcn_perm(q[u][2].y, q[u][3].y, 0x03020706u);
                        float s0 = dot2bf(b0, w0.y, dot2bf(a0, w0.x, -cv.x));
                        float s1 = dot2bf(b1, w0.y, dot2bf(a1, w0.x, -cv.y));
                        float s2 = dot2bf(b2, w0.y, dot2bf(a2, w0.x, -cv.z));
                        float s3 = dot2bf(b3, w0.y, dot2bf(a3, w0.x, -cv.w));
                        float s = (fabsf(s0) + fabsf(s1)) + (fabsf(s2) + fabsf(s3));
                        s = group16_sum(s);
                        float diff = __fmul_rn(s, 1.0f / 64.0f) * (m0 ? 1.0f : 0.0f);
                        costsum += diff;
                        counts  += (diff > 0.f) ? 1.0f : 0.0f;
                    }
                    // f = 1
                    {
                        unsigned a0 = __builtin_amdgcn_perm(q[u][4].x, q[u][5].x, 0x01000504u);
                        unsigned a1 = __builtin_amdgcn_perm(q[u][4].x, q[u][5].x, 0x03020706u);
                        unsigned a2 = __builtin_amdgcn_perm(q[u][4].y, q[u][5].y, 0x01000504u);
                        unsigned a3 = __builtin_amdgcn_perm(q[u][4].y, q[u][5].y, 0x03020706u);
                        unsigned b0 = __builtin_amdgcn_perm(q[u][6].x, q[u][7].x, 0x01000504u);
                        unsigned b1 = __builtin_amdgcn_perm(q[u][6].x, q[u][7].x, 0x03020706u);
                        unsigned b2 = __builtin_amdgcn_perm(q[u][6].y, q[u][7].y, 0x01000504u);
                        unsigned b3 = __builtin_amdgcn_perm(q[u][6].y, q[u][7].y, 0x03020706u);
                        float s0 = dot2bf(b0, w1.y, dot2bf(a0, w1.x, -cv.x));
                        float s1 = dot2bf(b1, w1.y, dot2bf(a1, w1.x, -cv.y));
                        float s2 = dot2bf(b2, w1.y, dot2bf(a2, w1.x, -cv.z));
                        float s3 = dot2bf(b3, w1.y, dot2bf(a3, w1.x, -cv.w));
                        float s = (fabsf(s0) + fabsf(s1)) + (fabsf(s2) + fabsf(s3));
                        s = group16_sum(s);
                        float diff = __fmul_rn(s, 1.0f / 64.0f) * (m1 ? 1.0f : 0.0f);
                        costsum += diff;
                        counts  += (diff > 0.f) ? 1.0f : 0.0f;
                    }
                    // cost via fast rcp: ~1e-7 rel err (threshold 2.9e-2), and
                    // EXACT zero preserved (costsum==0 -> 0*rcp(eps)=0) so the
                    // ==0.0 missing-fill semantics are unchanged.
                    float cost = costsum * __builtin_amdgcn_rcpf(__fadd_rn(counts, EPSF));
                    if (lane == 0) costb[px][dc] = cost;
                }
            }
        }
    }
    __syncthreads();

    // ---- Phase C: missing-fill + store (first 128 threads own the data) ----
    {
        int j = t >> 2, px = t & 3;          // j in [0,64); only j<32 used
        float v[3];
        if (t < 128) {
            float pm = 0.f;
            #pragma unroll
            for (int k = 0; k < 3; ++k) {
                v[k] = costb[px][j + 32 * k];
                pm = fmaxf(pm, v[k]);
            }
            pmax[j][px] = pm;
        }
        __syncthreads();
        if (t < PXB) {
            float cm = 0.f;
            #pragma unroll
            for (int jj = 0; jj < 32; ++jj) cm = fmaxf(cm, pmax[jj][t]);
            cmaxb[t] = cm;
        }
        __syncthreads();
        if (t < 128) {
            float cm = cmaxb[px];
            int x = xt * PXB + px;
            #pragma unroll
            for (int k = 0; k < 3; ++k) {
                int d = j + 32 * k;
                out[((size_t)(b * D_ + d) * H_ + y) * W_ + x] = (v[k] == 0.0f) ? cm : v[k];
            }
        }
    }
}

// ---------------------------------------------------------------------------
extern "C" void kernel_launch(void* const* d_in, const int* in_sizes, int n_in,
                              void* d_out, int out_size, void* d_ws, size_t ws_size,
                              hipStream_t stream) {
    const float* cur        = (const float*)d_in[0];  // [B,C,H,W]
    const float* lf         = (const float*)d_in[1];  // [B,F,C,H,W]
    const float* poses      = (const float*)d_in[2];  // [B,F,4,4]
    const float* K          = (const float*)d_in[3];  // [B,4,4]
    const float* invK       = (const float*)d_in[4];  // [B,4,4]
    const float* depth_bins = (const float*)d_in[5];  // [D]
    float* out = (float*)d_out;
    float* ws  = (float*)d_ws;

    prep_kernel<<<NT_BLKS, 256, 0, stream>>>(cur, lf, ws);
    mega_kernel<<<B_ * H_ * XT_, 256, 0, stream>>>(poses, K, invK, depth_bins, ws, out);
}

// Round 8
// 96.388 us; speedup vs baseline: 1.3790x; 1.0961x over previous
//
#include <hip/hip_runtime.h>
#include <math.h>

// Problem constants: B,F,C,H,W,D
constexpr int B_ = 2, F_ = 2, C_ = 64, H_ = 32, W_ = 104, D_ = 96;
constexpr int HW_ = H_ * W_;             // 3328
#define EPSF 1e-7f

// Workspace layout:
//   lfP  [B,F,H,W,C]  uint32 = packed (bf16 v[y][x][c], bf16 v[y][x+1][c])
//                     -- R18: pairing is depth-invariant, do it ONCE in prep.
//   curT [B,H,W,C]    f32    channel-last current feats
constexpr size_t LFP_ELEMS  = (size_t)B_ * F_ * HW_ * C_;   // 851968 uint32 = 3,407,872 B
constexpr size_t CURT_OFF_F = LFP_ELEMS;                    // float index == uint32 index

constexpr int NT_BLKS = (HW_ / 32) * (C_ / 32) * (B_ * F_ + B_);  // 1248
constexpr int PXB   = 4;        // pixels per block — 16B stores + reuse sweet spot
constexpr int XT_   = W_ / PXB; // 26 x-tiles
constexpr int DPAD  = D_ + 1;   // 97: row stride
constexpr int DPADI = D_ + 4;   // 100: int row stride (multiple of 4 -> int4 rows 16B aligned)

// Lesson ledger:
//  R13: conditional-def register pipeline -> local-mem demotion (+42MB WRITE). Never.
//  R14: __launch_bounds__(256,8) VGPR cap 64 -> spill (+20MB WRITE). Never squeeze.
//  R15: occupancy released, mega unchanged ~41µs -> occupancy is a dead lever.
//  R16: branchless loads removed the latency chain (FETCH 5.8MB, no spill) but
//       raised the VALU floor: 46.6µs, VALU-bound.
//  R17: perm+dot2 halved the dot math: 43.7µs, VALU-time 25.3->20.5µs. Perms
//       and addr math remained.
//  R18: (x0,x1) channel-pair packing moved to prep (depth-invariant!) ->
//       zero perms, dwordx4 corner loads (half count, half addr math).
//       dot2 stream bit-identical to R17.

// DPP butterfly add over 16-lane group — bit-identical to __shfl_xor chain
// (only commutes IEEE add operands). VALU-only: no ds_swizzle latency.
template<int CTRL>
__device__ __forceinline__ float dpp_add(float x) {
    int y = __builtin_amdgcn_update_dpp(0, __float_as_int(x), CTRL, 0xf, 0xf, true);
    return x + __int_as_float(y);
}
__device__ __forceinline__ float group16_sum(float s) {
    s = dpp_add<0xB1>(s);    // quad_perm(1,0,3,2)  == + lane^1
    s = dpp_add<0x4E>(s);    // quad_perm(2,3,0,1)  == + lane^2
    s = dpp_add<0x141>(s);   // row_half_mirror     == + lane^4-equiv
    s = dpp_add<0x140>(s);   // row_mirror          == + lane^8-equiv
    return s;
}

// f32 -> bf16 with round-to-nearest-even (weights/features finite; no NaN path)
__device__ __forceinline__ ushort f2bf(float f) {
    unsigned u = __float_as_uint(f);
    u += 0x7FFFu + ((u >> 16) & 1u);
    return (ushort)(u >> 16);
}

// v_dot2_f32_bf16: r = acc + a.lo*b.lo + a.hi*b.hi  (bf16x2 operands)
__device__ __forceinline__ float dot2bf(unsigned a, unsigned b, float acc) {
    float r;
    asm("v_dot2_f32_bf16 %0, %1, %2, %3" : "=v"(r) : "v"(a), "v"(b), "v"(acc));
    return r;
}

// ---------------------------------------------------------------------------
// Prep: channel-last transpose [C, HW] -> [HW, C] for 6 slices.
// lf slices (0..3): packed (x, x+1) bf16 channel pairs (uint32 per channel).
// cur slices (4..5): f32.
__global__ __launch_bounds__(256) void prep_kernel(
        const float* __restrict__ cur, const float* __restrict__ lf,
        float* __restrict__ ws) {
    __shared__ float tile[32][33];   // [chLocal][nLocal 0..32] — col 32 = n0+32
    int bid = blockIdx.x;
    int slice = bid / 208;            // 208 = 104 n-blocks * 2 c-blocks
    int rem   = bid % 208;
    int nb = rem % 104, cb = rem / 104;
    const float* inS = (slice < B_ * F_)
        ? lf  + (size_t)slice * C_ * HW_
        : cur + (size_t)(slice - B_ * F_) * C_ * HW_;
    int t = threadIdx.x;
    int tx = t & 31, ty = t >> 5;
    int n0 = nb * 32, c0 = cb * 32;
    int nx = (n0 + 32 < HW_) ? (n0 + 32) : (HW_ - 1);   // clamped extra column
    #pragma unroll
    for (int k = 0; k < 32; k += 8) {
        tile[ty + k][tx] = inS[(size_t)(c0 + ty + k) * HW_ + n0 + tx];
        if (tx == 0)
            tile[ty + k][32] = inS[(size_t)(c0 + ty + k) * HW_ + nx];
    }
    __syncthreads();
    if (slice < B_ * F_) {
        // packed pair: low bf16 = value at n (x), high bf16 = value at n+1 (x+1).
        // Row-boundary pairs (x=103) pack the next row's x=0 — finite garbage,
        // only ever multiplied by weight 0 (gx <= W-2 -> x0 <= 102).
        unsigned* outS = (unsigned*)ws + (size_t)slice * HW_ * C_;
        #pragma unroll
        for (int k = 0; k < 32; k += 8) {
            unsigned lo = f2bf(tile[tx][ty + k]);
            unsigned hi = f2bf(tile[tx][ty + k + 1]);
            outS[(size_t)(n0 + ty + k) * C_ + c0 + tx] = lo | (hi << 16);
        }
    } else {
        float* outS = ws + CURT_OFF_F + (size_t)(slice - B_ * F_) * HW_ * C_;
        #pragma unroll
        for (int k = 0; k < 32; k += 8)
            outS[(size_t)(n0 + ty + k) * C_ + c0 + tx] = tile[tx][ty + k];
    }
}

// ---------------------------------------------------------------------------
// Mega kernel (R18): block = (b, y, xt) covering 4 px * ALL 96 depths * 2
// frames. 256 threads = 4 halves x (16 lanes x 4 px); each half walks 24
// depths. Phase A: 768 projections -> LDS {offset, packed-bf16 weight pairs}
// (projection FP op order bit-identical — mask-critical, do not touch).
// Phase B: branchless dwordx4 corner-row loads in pairs-of-depths (8 loads in
// flight), v_dot2_f32_bf16 bilinear (acc starts at -cv), DPP channel reduce,
// v_rcp cost. Phase C: in-block missing-fill + store.
__global__ __launch_bounds__(256, 4) void mega_kernel(
        const float* __restrict__ poses, const float* __restrict__ K,
        const float* __restrict__ invK, const float* __restrict__ depth_bins,
        const float* __restrict__ ws, float* __restrict__ out) {
    int t   = threadIdx.x;
    int bid = blockIdx.x;
    int xt  = bid % XT_;  int r = bid / XT_;
    int y   = r % H_;
    int b   = r / H_;

    if (y < 2 || y >= H_ - 2) {
        // whole row masked: cost column all-zero -> column max 0 -> output 0
        for (int k = t; k < PXB * D_; k += 256) {
            int d = k >> 2, px = k & 3;
            out[((size_t)(b * D_ + d) * H_ + y) * W_ + xt * PXB + px] = 0.0f;
        }
        return;   // block-uniform exit
    }

    __shared__ alignas(16) int offsL[F_][PXB][DPADI];
    __shared__ alignas(16) uint2 wtsL[F_][PXB][DPAD];   // packed bf16 weight pairs
    __shared__ float  costb[PXB][DPAD];
    __shared__ float  pmax[32][PXB];
    __shared__ float  cmaxb[PXB];

    // ---- Phase A: projections (FP op order identical to R9/R11) ----
    {
        // px = (t + 256k) & 3 = t & 3 — invariant across k. Hoist cam/interior.
        int pxA = t & 3;
        int xA  = xt * PXB + pxA;
        const float* iK = invK + (size_t)b * 16;
        float xf = (float)xA, yf = (float)y;
        float cam0 = __fmul_rn(iK[0], xf); cam0 = __fmaf_rn(iK[1], yf, cam0); cam0 = __fmaf_rn(iK[2],  1.0f, cam0);
        float cam1 = __fmul_rn(iK[4], xf); cam1 = __fmaf_rn(iK[5], yf, cam1); cam1 = __fmaf_rn(iK[6],  1.0f, cam1);
        float cam2 = __fmul_rn(iK[8], xf); cam2 = __fmaf_rn(iK[9], yf, cam2); cam2 = __fmaf_rn(iK[10], 1.0f, cam2);
        bool interior = (xA >= 2) && (xA <= W_ - 3);   // y already interior

        #pragma unroll
        for (int f = 0; f < F_; ++f) {
            const float* Kb   = K + (size_t)b * 16;
            const float* pose = poses + (size_t)(b * F_ + f) * 16;
            float P[12];
            #pragma unroll
            for (int i = 0; i < 3; ++i) {
                #pragma unroll
                for (int k = 0; k < 4; ++k) {
                    float acc = __fmul_rn(Kb[i*4+0], pose[0*4+k]);
                    acc = __fmaf_rn(Kb[i*4+1], pose[1*4+k], acc);
                    acc = __fmaf_rn(Kb[i*4+2], pose[2*4+k], acc);
                    acc = __fmaf_rn(Kb[i*4+3], pose[3*4+k], acc);
                    P[i*4+k] = acc;
                }
            }
            float vs = 0.f;
            #pragma unroll
            for (int j = 0; j < 16; ++j) vs += pose[j];
            bool valid = (vs != 0.f);

            #pragma unroll
            for (int k = 0; k < 2; ++k) {
                int idx = t + 256 * k;          // records [0,384) = dd*4 + px
                if (idx < PXB * D_) {
                    int dd = idx >> 2;
                    float depth = depth_bins[dd];
                    float p0 = __fmul_rn(depth, cam0);
                    float p1 = __fmul_rn(depth, cam1);
                    float p2 = __fmul_rn(depth, cam2);
                    float c0 = __fmul_rn(P[0], p0); c0 = __fmaf_rn(P[1], p1, c0); c0 = __fmaf_rn(P[2],  p2, c0); c0 = __fmaf_rn(P[3],  1.0f, c0);
                    float c1 = __fmul_rn(P[4], p0); c1 = __fmaf_rn(P[5], p1, c1); c1 = __fmaf_rn(P[6],  p2, c1); c1 = __fmaf_rn(P[7],  1.0f, c1);
                    float c2 = __fmul_rn(P[8], p0); c2 = __fmaf_rn(P[9], p1, c2); c2 = __fmaf_rn(P[10], p2, c2); c2 = __fmaf_rn(P[11], 1.0f, c2);
                    float denom = __fadd_rn(c2, EPSF);
                    float gx = c0 / denom;   // IEEE div — mask-critical
                    float gy = c1 / denom;
                    bool m = valid && interior && (gx >= 2.0f) && (gx <= (float)(W_ - 2))
                                               && (gy >= 2.0f) && (gy <= (float)(H_ - 2));
                    if (m) {
                        float x0f = floorf(gx), y0f = floorf(gy);
                        int   x0  = (int)x0f,   y0  = (int)y0f;
                        float wx1 = gx - x0f, wy1 = gy - y0f;
                        float wx0 = 1.f - wx1, wy0 = 1.f - wy1;
                        // packed bf16 weight pairs: low bf16 = x0 weight
                        unsigned wlo = ((unsigned)f2bf(wy0 * wx1) << 16) | f2bf(wy0 * wx0);
                        unsigned whi = ((unsigned)f2bf(wy1 * wx1) << 16) | f2bf(wy1 * wx0);
                        wtsL[f][pxA][dd] = make_uint2(wlo, whi);
                        offsL[f][pxA][dd] = (y0 * W_ + x0) * C_;   // uint32-element offset
                    } else {
                        offsL[f][pxA][dd] = -1;
                        // exact bf16 zeros: finite corners * 0.0 = 0.0 -> a = -cv,
                        // killed by the m-multiply (semantics preserved).
                        wtsL[f][pxA][dd] = make_uint2(0u, 0u);
                    }
                }
            }
        }
    }
    __syncthreads();

    // ---- Phase B: branchless dwordx4 loads + dot2 blend + DPP reduce ----
    {
        int lane = t & 15, px = (t >> 4) & 3, half = t >> 6;  // half in [0,4)
        int x = xt * PXB + px;
        const float4 cv = *(const float4*)(ws + CURT_OFF_F
                            + ((size_t)((b * H_ + y) * W_ + x)) * C_ + lane * 4);
        // per frame: row y0 base and row y0+1 base (paired buffer, uint32 elems)
        const unsigned* pfbase = (const unsigned*)ws;
        const unsigned* pf0a = pfbase + (size_t)(b * F_ + 0) * HW_ * C_ + lane * 4;
        const unsigned* pf0b = pf0a + W_ * C_;
        const unsigned* pf1a = pfbase + (size_t)(b * F_ + 1) * HW_ * C_ + lane * 4;
        const unsigned* pf1b = pf1a + W_ * C_;

        int dbeg = half * (D_ / 4);
        for (int ki4 = 0; ki4 < D_ / 16; ++ki4) {     // 6 groups of 4 depths
            int dc4 = dbeg + ki4 * 4;
            int4 oq0 = *(const int4*)&offsL[0][px][dc4];   // one ds_read_b128 / frame / 4 depths
            int4 oq1 = *(const int4*)&offsL[1][px][dc4];
            int oa0[4] = {oq0.x, oq0.y, oq0.z, oq0.w};     // static-indexed (unrolled below)
            int oa1[4] = {oq1.x, oq1.y, oq1.z, oq1.w};

            #pragma unroll
            for (int jp = 0; jp < 2; ++jp) {          // pairs: 8 loads, then 2 computes
                // q[] is statically indexed and UNCONDITIONALLY written (R13
                // lesson: conditional defs demote to scratch).
                uint4 q[2][4];
                #pragma unroll
                for (int u = 0; u < 2; ++u) {
                    int j = jp * 2 + u;
                    int oc0 = oa0[j], oc1 = oa1[j];
                    int os0 = oc0 & ~(oc0 >> 31);     // max(oc,0): masked -> slice start (safe,
                    int os1 = oc1 & ~(oc1 >> 31);     // finite data; zero weights kill the value)
                    q[u][0] = *(const uint4*)(pf0a + os0);   // f0 row a: 4 ch pairs
                    q[u][1] = *(const uint4*)(pf0b + os0);   // f0 row b
                    q[u][2] = *(const uint4*)(pf1a + os1);   // f1 row a
                    q[u][3] = *(const uint4*)(pf1b + os1);   // f1 row b
                }
                #pragma unroll
                for (int u = 0; u < 2; ++u) {
                    int j = jp * 2 + u;
                    int dc = dc4 + j;
                    uint2 w0 = wtsL[0][px][dc], w1 = wtsL[1][px][dc];
                    bool m0 = (oa0[j] >= 0), m1 = (oa1[j] >= 0);
                    uint4 A0 = q[u][0], B0 = q[u][1];
                    uint4 A1 = q[u][2], B1 = q[u][3];

                    float costsum = 0.f, counts = 0.f;
                    // f = 0: dot2 blends 2 corners/inst; row-a dot2 starts from
                    // -cv (fold the sub). Bit-identical op stream to R17.
                    {
                        float s0 = dot2bf(B0.x, w0.y, dot2bf(A0.x, w0.x, -cv.x));
                        float s1 = dot2bf(B0.y, w0.y, dot2bf(A0.y, w0.x, -cv.y));
                        float s2 = dot2bf(B0.z, w0.y, dot2bf(A0.z, w0.x, -cv.z));
                        float s3 = dot2bf(B0.w, w0.y, dot2bf(A0.w, w0.x, -cv.w));
                        float s = (fabsf(s0) + fabsf(s1)) + (fabsf(s2) + fabsf(s3));
                        s = group16_sum(s);
                        float diff = __fmul_rn(s, 1.0f / 64.0f) * (m0 ? 1.0f : 0.0f);
                        costsum += diff;
                        counts  += (diff > 0.f) ? 1.0f : 0.0f;
                    }
                    // f = 1
                    {
                        float s0 = dot2bf(B1.x, w1.y, dot2bf(A1.x, w1.x, -cv.x));
                        float s1 = dot2bf(B1.y, w1.y, dot2bf(A1.y, w1.x, -cv.y));
                        float s2 = dot2bf(B1.z, w1.y, dot2bf(A1.z, w1.x, -cv.z));
                        float s3 = dot2bf(B1.w, w1.y, dot2bf(A1.w, w1.x, -cv.w));
                        float s = (fabsf(s0) + fabsf(s1)) + (fabsf(s2) + fabsf(s3));
                        s = group16_sum(s);
                        float diff = __fmul_rn(s, 1.0f / 64.0f) * (m1 ? 1.0f : 0.0f);
                        costsum += diff;
                        counts  += (diff > 0.f) ? 1.0f : 0.0f;
                    }
                    // cost via fast rcp: ~1e-7 rel err (threshold 2.9e-2), and
                    // EXACT zero preserved (costsum==0 -> 0*rcp(eps)=0) so the
                    // ==0.0 missing-fill semantics are unchanged.
                    float cost = costsum * __builtin_amdgcn_rcpf(__fadd_rn(counts, EPSF));
                    if (lane == 0) costb[px][dc] = cost;
                }
            }
        }
    }
    __syncthreads();

    // ---- Phase C: missing-fill + store (first 128 threads own the data) ----
    {
        int j = t >> 2, px = t & 3;          // j in [0,64); only j<32 used
        float v[3];
        if (t < 128) {
            float pm = 0.f;
            #pragma unroll
            for (int k = 0; k < 3; ++k) {
                v[k] = costb[px][j + 32 * k];
                pm = fmaxf(pm, v[k]);
            }
            pmax[j][px] = pm;
        }
        __syncthreads();
        if (t < PXB) {
            float cm = 0.f;
            #pragma unroll
            for (int jj = 0; jj < 32; ++jj) cm = fmaxf(cm, pmax[jj][t]);
            cmaxb[t] = cm;
        }
        __syncthreads();
        if (t < 128) {
            float cm = cmaxb[px];
            int x = xt * PXB + px;
            #pragma unroll
            for (int k = 0; k < 3; ++k) {
                int d = j + 32 * k;
                out[((size_t)(b * D_ + d) * H_ + y) * W_ + x] = (v[k] == 0.0f) ? cm : v[k];
            }
        }
    }
}

// ---------------------------------------------------------------------------
extern "C" void kernel_launch(void* const* d_in, const int* in_sizes, int n_in,
                              void* d_out, int out_size, void* d_ws, size_t ws_size,
                              hipStream_t stream) {
    const float* cur        = (const float*)d_in[0];  // [B,C,H,W]
    const float* lf         = (const float*)d_in[1];  // [B,F,C,H,W]
    const float* poses      = (const float*)d_in[2];  // [B,F,4,4]
    const float* K          = (const float*)d_in[3];  // [B,4,4]
    const float* invK       = (const float*)d_in[4];  // [B,4,4]
    const float* depth_bins = (const float*)d_in[5];  // [D]
    float* out = (float*)d_out;
    float* ws  = (float*)d_ws;

    prep_kernel<<<NT_BLKS, 256, 0, stream>>>(cur, lf, ws);
    mega_kernel<<<B_ * H_ * XT_, 256, 0, stream>>>(poses, K, invK, depth_bins, ws, out);
}

// Round 9
// 95.279 us; speedup vs baseline: 1.3951x; 1.0116x over previous
//
#include <hip/hip_runtime.h>
#include <math.h>

// Problem constants: B,F,C,H,W,D
constexpr int B_ = 2, F_ = 2, C_ = 64, H_ = 32, W_ = 104, D_ = 96;
constexpr int HW_ = H_ * W_;             // 3328
#define EPSF 1e-7f

// Workspace layout:
//   lfP  [B,F,H,W,C]  uint32 = packed (bf16 v[y][x][c], bf16 v[y][x+1][c])
//                     -- R18: pairing is depth-invariant, done ONCE in prep.
//   curT [B,H,W,C]    f32    channel-last current feats
constexpr size_t LFP_ELEMS  = (size_t)B_ * F_ * HW_ * C_;   // 851968 uint32
constexpr size_t CURT_OFF_F = LFP_ELEMS;                    // float index == uint32 index

constexpr int NT_BLKS = (HW_ / 32) * (C_ / 32) * (B_ * F_ + B_);  // 1248
constexpr int PXB   = 4;        // pixels per block — 16B stores + reuse sweet spot
constexpr int XT_   = W_ / PXB; // 26 x-tiles
constexpr int DPAD  = D_ + 1;   // 97: row stride
constexpr int DPADI = D_ + 4;   // 100: int row stride (mult of 4 -> int4 rows 16B aligned;
                                //      pads [96..99]=0 feed the R19 lookahead safely)

// Lesson ledger:
//  R13: conditional-def register pipeline -> local-mem demotion (+42MB WRITE). Never.
//  R14: __launch_bounds__(256,8) VGPR cap 64 -> spill (+20MB WRITE). Never squeeze.
//  R15: occupancy released, unchanged -> occupancy is a dead lever here.
//  R16: branchless loads kill the latency chain but raise the VALU floor.
//  R17/R18: dot2 + prep-side pairing: VALU floor cut ~45%. 96.4µs total.
//  R19: loads are UNCONDITIONAL since R16 -> explicit distance-1 pipeline is
//       now spill-proof (two named q stages, static indexing, uncond writes).
//       Mask folded into Phase A: offsL pre-clamped, mm=m/64 packed in wtsL.z.

// DPP butterfly add over 16-lane group — bit-identical to __shfl_xor chain
// (only commutes IEEE add operands). VALU-only: no ds_swizzle latency.
template<int CTRL>
__device__ __forceinline__ float dpp_add(float x) {
    int y = __builtin_amdgcn_update_dpp(0, __float_as_int(x), CTRL, 0xf, 0xf, true);
    return x + __int_as_float(y);
}
__device__ __forceinline__ float group16_sum(float s) {
    s = dpp_add<0xB1>(s);    // quad_perm(1,0,3,2)  == + lane^1
    s = dpp_add<0x4E>(s);    // quad_perm(2,3,0,1)  == + lane^2
    s = dpp_add<0x141>(s);   // row_half_mirror     == + lane^4-equiv
    s = dpp_add<0x140>(s);   // row_mirror          == + lane^8-equiv
    return s;
}

// f32 -> bf16 with round-to-nearest-even (weights/features finite; no NaN path)
__device__ __forceinline__ ushort f2bf(float f) {
    unsigned u = __float_as_uint(f);
    u += 0x7FFFu + ((u >> 16) & 1u);
    return (ushort)(u >> 16);
}

// v_dot2_f32_bf16: r = acc + a.lo*b.lo + a.hi*b.hi  (bf16x2 operands)
__device__ __forceinline__ float dot2bf(unsigned a, unsigned b, float acc) {
    float r;
    asm("v_dot2_f32_bf16 %0, %1, %2, %3" : "=v"(r) : "v"(a), "v"(b), "v"(acc));
    return r;
}

// ---------------------------------------------------------------------------
// Prep: channel-last transpose [C, HW] -> [HW, C] for 6 slices.
// lf slices (0..3): packed (x, x+1) bf16 channel pairs (uint32 per channel).
// cur slices (4..5): f32.
__global__ __launch_bounds__(256) void prep_kernel(
        const float* __restrict__ cur, const float* __restrict__ lf,
        float* __restrict__ ws) {
    __shared__ float tile[32][33];   // [chLocal][nLocal 0..32] — col 32 = n0+32
    int bid = blockIdx.x;
    int slice = bid / 208;            // 208 = 104 n-blocks * 2 c-blocks
    int rem   = bid % 208;
    int nb = rem % 104, cb = rem / 104;
    const float* inS = (slice < B_ * F_)
        ? lf  + (size_t)slice * C_ * HW_
        : cur + (size_t)(slice - B_ * F_) * C_ * HW_;
    int t = threadIdx.x;
    int tx = t & 31, ty = t >> 5;
    int n0 = nb * 32, c0 = cb * 32;
    int nx = (n0 + 32 < HW_) ? (n0 + 32) : (HW_ - 1);   // clamped extra column
    #pragma unroll
    for (int k = 0; k < 32; k += 8) {
        tile[ty + k][tx] = inS[(size_t)(c0 + ty + k) * HW_ + n0 + tx];
        if (tx == 0)
            tile[ty + k][32] = inS[(size_t)(c0 + ty + k) * HW_ + nx];
    }
    __syncthreads();
    if (slice < B_ * F_) {
        // packed pair: low bf16 = value at n (x), high bf16 = value at n+1 (x+1).
        // Row-boundary pairs (x=103) pack the next row's x=0 — finite garbage,
        // only ever multiplied by weight 0 (gx <= W-2 -> x0 <= 102).
        unsigned* outS = (unsigned*)ws + (size_t)slice * HW_ * C_;
        #pragma unroll
        for (int k = 0; k < 32; k += 8) {
            unsigned lo = f2bf(tile[tx][ty + k]);
            unsigned hi = f2bf(tile[tx][ty + k + 1]);
            outS[(size_t)(n0 + ty + k) * C_ + c0 + tx] = lo | (hi << 16);
        }
    } else {
        float* outS = ws + CURT_OFF_F + (size_t)(slice - B_ * F_) * HW_ * C_;
        #pragma unroll
        for (int k = 0; k < 32; k += 8)
            outS[(size_t)(n0 + ty + k) * C_ + c0 + tx] = tile[tx][ty + k];
    }
}

// ---------------------------------------------------------------------------
// Mega kernel (R19): block = (b, y, xt) covering 4 px * ALL 96 depths * 2
// frames. 256 threads = 4 halves x (16 lanes x 4 px); each half walks 24
// depths. Phase A: 768 projections -> LDS {pre-clamped offset, uint4 weights
// {wlo, whi, mm, 0}} (projection FP op order bit-identical — mask-critical).
// Phase B: explicit distance-1 software pipeline — loads for depth d+1 issue
// before compute of depth d; two named uint4[4] stages, statically indexed,
// unconditionally written (spill-proof). dot2 bilinear, DPP reduce, v_rcp.
// Phase C: in-block missing-fill + store.
__global__ __launch_bounds__(256, 4) void mega_kernel(
        const float* __restrict__ poses, const float* __restrict__ K,
        const float* __restrict__ invK, const float* __restrict__ depth_bins,
        const float* __restrict__ ws, float* __restrict__ out) {
    int t   = threadIdx.x;
    int bid = blockIdx.x;
    int xt  = bid % XT_;  int r = bid / XT_;
    int y   = r % H_;
    int b   = r / H_;

    if (y < 2 || y >= H_ - 2) {
        // whole row masked: cost column all-zero -> column max 0 -> output 0
        for (int k = t; k < PXB * D_; k += 256) {
            int d = k >> 2, px = k & 3;
            out[((size_t)(b * D_ + d) * H_ + y) * W_ + xt * PXB + px] = 0.0f;
        }
        return;   // block-uniform exit
    }

    __shared__ alignas(16) int offsL[F_][PXB][DPADI];
    __shared__ alignas(16) uint4 wtsL[F_][PXB][DPAD];  // {wlo, whi, mm, 0}
    __shared__ float  costb[PXB][DPAD];
    __shared__ float  pmax[32][PXB];
    __shared__ float  cmaxb[PXB];

    // ---- Phase A: projections (FP op order identical to R9/R11) ----
    {
        // pads [96..99] = 0 (safe clamped offset for the Phase-B lookahead)
        if (t < 32) {
            int fp = t >> 4, pp = (t >> 2) & 3, kp = t & 3;
            offsL[fp][pp][D_ + kp] = 0;
        }
        // px = (t + 256k) & 3 = t & 3 — invariant across k. Hoist cam/interior.
        int pxA = t & 3;
        int xA  = xt * PXB + pxA;
        const float* iK = invK + (size_t)b * 16;
        float xf = (float)xA, yf = (float)y;
        float cam0 = __fmul_rn(iK[0], xf); cam0 = __fmaf_rn(iK[1], yf, cam0); cam0 = __fmaf_rn(iK[2],  1.0f, cam0);
        float cam1 = __fmul_rn(iK[4], xf); cam1 = __fmaf_rn(iK[5], yf, cam1); cam1 = __fmaf_rn(iK[6],  1.0f, cam1);
        float cam2 = __fmul_rn(iK[8], xf); cam2 = __fmaf_rn(iK[9], yf, cam2); cam2 = __fmaf_rn(iK[10], 1.0f, cam2);
        bool interior = (xA >= 2) && (xA <= W_ - 3);   // y already interior

        #pragma unroll
        for (int f = 0; f < F_; ++f) {
            const float* Kb   = K + (size_t)b * 16;
            const float* pose = poses + (size_t)(b * F_ + f) * 16;
            float P[12];
            #pragma unroll
            for (int i = 0; i < 3; ++i) {
                #pragma unroll
                for (int k = 0; k < 4; ++k) {
                    float acc = __fmul_rn(Kb[i*4+0], pose[0*4+k]);
                    acc = __fmaf_rn(Kb[i*4+1], pose[1*4+k], acc);
                    acc = __fmaf_rn(Kb[i*4+2], pose[2*4+k], acc);
                    acc = __fmaf_rn(Kb[i*4+3], pose[3*4+k], acc);
                    P[i*4+k] = acc;
                }
            }
            float vs = 0.f;
            #pragma unroll
            for (int j = 0; j < 16; ++j) vs += pose[j];
            bool valid = (vs != 0.f);

            #pragma unroll
            for (int k = 0; k < 2; ++k) {
                int idx = t + 256 * k;          // records [0,384) = dd*4 + px
                if (idx < PXB * D_) {
                    int dd = idx >> 2;
                    float depth = depth_bins[dd];
                    float p0 = __fmul_rn(depth, cam0);
                    float p1 = __fmul_rn(depth, cam1);
                    float p2 = __fmul_rn(depth, cam2);
                    float c0 = __fmul_rn(P[0], p0); c0 = __fmaf_rn(P[1], p1, c0); c0 = __fmaf_rn(P[2],  p2, c0); c0 = __fmaf_rn(P[3],  1.0f, c0);
                    float c1 = __fmul_rn(P[4], p0); c1 = __fmaf_rn(P[5], p1, c1); c1 = __fmaf_rn(P[6],  p2, c1); c1 = __fmaf_rn(P[7],  1.0f, c1);
                    float c2 = __fmul_rn(P[8], p0); c2 = __fmaf_rn(P[9], p1, c2); c2 = __fmaf_rn(P[10], p2, c2); c2 = __fmaf_rn(P[11], 1.0f, c2);
                    float denom = __fadd_rn(c2, EPSF);
                    float gx = c0 / denom;   // IEEE div — mask-critical
                    float gy = c1 / denom;
                    bool m = valid && interior && (gx >= 2.0f) && (gx <= (float)(W_ - 2))
                                               && (gy >= 2.0f) && (gy <= (float)(H_ - 2));
                    if (m) {
                        float x0f = floorf(gx), y0f = floorf(gy);
                        int   x0  = (int)x0f,   y0  = (int)y0f;
                        float wx1 = gx - x0f, wy1 = gy - y0f;
                        float wx0 = 1.f - wx1, wy0 = 1.f - wy1;
                        // packed bf16 weight pairs: low bf16 = x0 weight;
                        // .z = mm = 1/64 (mask folded into the cost scale)
                        unsigned wlo = ((unsigned)f2bf(wy0 * wx1) << 16) | f2bf(wy0 * wx0);
                        unsigned whi = ((unsigned)f2bf(wy1 * wx1) << 16) | f2bf(wy1 * wx0);
                        wtsL[f][pxA][dd] = make_uint4(wlo, whi,
                                                      __float_as_uint(1.0f / 64.0f), 0u);
                        offsL[f][pxA][dd] = (y0 * W_ + x0) * C_;   // uint32-elem offset, >=0
                    } else {
                        offsL[f][pxA][dd] = 0;       // pre-clamped safe offset
                        // mm = 0 kills the value exactly: s*0 = +0 (s finite).
                        wtsL[f][pxA][dd] = make_uint4(0u, 0u, 0u, 0u);
                    }
                }
            }
        }
    }
    __syncthreads();

    // ---- Phase B: distance-1 pipelined dwordx4 loads + dot2 + DPP reduce ----
    {
        int lane = t & 15, px = (t >> 4) & 3, half = t >> 6;  // half in [0,4)
        int x = xt * PXB + px;
        const float4 cv = *(const float4*)(ws + CURT_OFF_F
                            + ((size_t)((b * H_ + y) * W_ + x)) * C_ + lane * 4);
        // per frame: row y0 base and row y0+1 base (paired buffer, uint32 elems)
        const unsigned* pfbase = (const unsigned*)ws;
        const unsigned* pf0a = pfbase + (size_t)(b * F_ + 0) * HW_ * C_ + lane * 4;
        const unsigned* pf0b = pf0a + W_ * C_;
        const unsigned* pf1a = pfbase + (size_t)(b * F_ + 1) * HW_ * C_ + lane * 4;
        const unsigned* pf1b = pf1a + W_ * C_;

        // issue 4 corner-row loads for one depth into a named stage (uncond)
        #define ISSUE(dst, o0, o1) do {                       \
            dst[0] = *(const uint4*)(pf0a + (o0));            \
            dst[1] = *(const uint4*)(pf0b + (o0));            \
            dst[2] = *(const uint4*)(pf1a + (o1));            \
            dst[3] = *(const uint4*)(pf1b + (o1));            \
        } while (0)

        // compute one depth from a named stage; FP stream identical to R18
        // (diff = (s*1/64)*1 == s*(1/64) = s*mm; masked s*0 == +0)
        #define COMPUTE(dc, q) do {                                            \
            uint4 w0 = wtsL[0][px][dc];                                        \
            uint4 w1 = wtsL[1][px][dc];                                        \
            float s0 = dot2bf(q[1].x, w0.y, dot2bf(q[0].x, w0.x, -cv.x));      \
            float s1 = dot2bf(q[1].y, w0.y, dot2bf(q[0].y, w0.x, -cv.y));      \
            float s2 = dot2bf(q[1].z, w0.y, dot2bf(q[0].z, w0.x, -cv.z));      \
            float s3 = dot2bf(q[1].w, w0.y, dot2bf(q[0].w, w0.x, -cv.w));      \
            float sA = (fabsf(s0) + fabsf(s1)) + (fabsf(s2) + fabsf(s3));      \
            sA = group16_sum(sA);                                              \
            float u0 = dot2bf(q[3].x, w1.y, dot2bf(q[2].x, w1.x, -cv.x));      \
            float u1 = dot2bf(q[3].y, w1.y, dot2bf(q[2].y, w1.x, -cv.y));      \
            float u2 = dot2bf(q[3].z, w1.y, dot2bf(q[2].z, w1.x, -cv.z));      \
            float u3 = dot2bf(q[3].w, w1.y, dot2bf(q[2].w, w1.x, -cv.w));      \
            float sB = (fabsf(u0) + fabsf(u1)) + (fabsf(u2) + fabsf(u3));      \
            sB = group16_sum(sB);                                              \
            float diff0 = __fmul_rn(sA, __uint_as_float(w0.z));                \
            float diff1 = __fmul_rn(sB, __uint_as_float(w1.z));                \
            float costsum = diff0 + diff1;                                     \
            float counts = ((diff0 > 0.f) ? 1.0f : 0.0f)                       \
                         + ((diff1 > 0.f) ? 1.0f : 0.0f);                      \
            float cost = costsum * __builtin_amdgcn_rcpf(__fadd_rn(counts, EPSF)); \
            if (lane == 0) costb[px][dc] = cost;                               \
        } while (0)

        int dbeg = half * (D_ / 4);                       // 24 depths per half
        int4 c0v = *(const int4*)&offsL[0][px][dbeg];     // current group offsets
        int4 c1v = *(const int4*)&offsL[1][px][dbeg];
        uint4 qa[4], qb[4];                               // two pipeline stages
        ISSUE(qa, c0v.x, c1v.x);                          // prologue: depth 0

        for (int g = 0; g < 6; ++g) {                     // 6 groups of 4 depths
            int dc0 = dbeg + g * 4;
            ISSUE(qb, c0v.y, c1v.y);
            COMPUTE(dc0 + 0, qa);
            ISSUE(qa, c0v.z, c1v.z);
            COMPUTE(dc0 + 1, qb);
            ISSUE(qb, c0v.w, c1v.w);
            COMPUTE(dc0 + 2, qa);
            // next group's offsets (g=5 & half=3 -> pads [96..99] = 0, safe)
            c0v = *(const int4*)&offsL[0][px][dc0 + 4];
            c1v = *(const int4*)&offsL[1][px][dc0 + 4];
            ISSUE(qa, c0v.x, c1v.x);                      // next group depth 0
            COMPUTE(dc0 + 3, qb);
        }
        // final prefetched qa (from pad/next-half offsets) intentionally unused

        #undef ISSUE
        #undef COMPUTE
    }
    __syncthreads();

    // ---- Phase C: missing-fill + store (first 128 threads own the data) ----
    {
        int j = t >> 2, px = t & 3;          // j in [0,64); only j<32 used
        float v[3];
        if (t < 128) {
            float pm = 0.f;
            #pragma unroll
            for (int k = 0; k < 3; ++k) {
                v[k] = costb[px][j + 32 * k];
                pm = fmaxf(pm, v[k]);
            }
            pmax[j][px] = pm;
        }
        __syncthreads();
        if (t < PXB) {
            float cm = 0.f;
            #pragma unroll
            for (int jj = 0; jj < 32; ++jj) cm = fmaxf(cm, pmax[jj][t]);
            cmaxb[t] = cm;
        }
        __syncthreads();
        if (t < 128) {
            float cm = cmaxb[px];
            int x = xt * PXB + px;
            #pragma unroll
            for (int k = 0; k < 3; ++k) {
                int d = j + 32 * k;
                out[((size_t)(b * D_ + d) * H_ + y) * W_ + x] = (v[k] == 0.0f) ? cm : v[k];
            }
        }
    }
}

// ---------------------------------------------------------------------------
extern "C" void kernel_launch(void* const* d_in, const int* in_sizes, int n_in,
                              void* d_out, int out_size, void* d_ws, size_t ws_size,
                              hipStream_t stream) {
    const float* cur        = (const float*)d_in[0];  // [B,C,H,W]
    const float* lf         = (const float*)d_in[1];  // [B,F,C,H,W]
    const float* poses      = (const float*)d_in[2];  // [B,F,4,4]
    const float* K          = (const float*)d_in[3];  // [B,4,4]
    const float* invK       = (const float*)d_in[4];  // [B,4,4]
    const float* depth_bins = (const float*)d_in[5];  // [D]
    float* out = (float*)d_out;
    float* ws  = (float*)d_ws;

    prep_kernel<<<NT_BLKS, 256, 0, stream>>>(cur, lf, ws);
    mega_kernel<<<B_ * H_ * XT_, 256, 0, stream>>>(poses, K, invK, depth_bins, ws, out);
}

// Round 12
// 94.017 us; speedup vs baseline: 1.4138x; 1.0134x over previous
//
#include <hip/hip_runtime.h>
#include <math.h>

// Problem constants: B,F,C,H,W,D
constexpr int B_ = 2, F_ = 2, C_ = 64, H_ = 32, W_ = 104, D_ = 96;
constexpr int HW_ = H_ * W_;             // 3328
#define EPSF 1e-7f

// Workspace layout:
//   lfP  [B,F,H,W,C]  uint32 = packed (bf16 v[y][x][c], bf16 v[y][x+1][c])
//                     -- R18: pairing is depth-invariant, done ONCE in prep.
//   curT [B,H,W,C]    f32    channel-last current feats
constexpr size_t LFP_ELEMS  = (size_t)B_ * F_ * HW_ * C_;   // 851968 uint32
constexpr size_t CURT_OFF_F = LFP_ELEMS;                    // float index == uint32 index

constexpr int NT_BLKS = (HW_ / 32) * (C_ / 32) * (B_ * F_ + B_);  // 1248
constexpr int PXB   = 4;        // pixels per block — 16B stores + reuse sweet spot
constexpr int XT_   = W_ / PXB; // 26 x-tiles
constexpr int DPAD  = D_ + 1;   // 97: row stride
constexpr int DPADI = D_ + 4;   // 100: int row stride (mult of 4 -> int4 rows 16B aligned;
                                //      pads [96..99]=0 feed the pipeline lookahead safely)

// Lesson ledger:
//  R13: conditional-def register pipeline -> local-mem demotion (+42MB WRITE). Never.
//  R14: __launch_bounds__(256,8) VGPR cap 64 -> spill (+20MB WRITE). Never squeeze.
//  R15: occupancy released, unchanged -> occupancy is a dead lever here.
//  R16: branchless loads kill the latency chain but raise the VALU floor.
//  R17/R18: dot2 + prep-side pairing: VALU floor cut ~45%. 96.4µs total.
//  R19: explicit distance-1 pipeline + mask folded into wtsL.z: 95.3µs (best).
//  R20/R21: FAILED — fusing frames BEFORE the DPP reduce (cost =
//       group16_sum(sA*mm0'+sB*mm1')) broke correctness in two independent
//       implementations (LDS-RMW count-fold AND register-side count-fold),
//       with run-inconsistent garbage outputs. Mechanism not isolated.
//       KEEP the reduce-then-scale order: sA,sB reduced separately, .z
//       multiply AFTER the tree. Do not re-attempt without a debug loop.
//  R22: revert to R19 verbatim — session best-known-good.

// DPP butterfly add over 16-lane group — bit-identical to __shfl_xor chain
// (only commutes IEEE add operands). VALU-only: no ds_swizzle latency.
template<int CTRL>
__device__ __forceinline__ float dpp_add(float x) {
    int y = __builtin_amdgcn_update_dpp(0, __float_as_int(x), CTRL, 0xf, 0xf, true);
    return x + __int_as_float(y);
}
__device__ __forceinline__ float group16_sum(float s) {
    s = dpp_add<0xB1>(s);    // quad_perm(1,0,3,2)  == + lane^1
    s = dpp_add<0x4E>(s);    // quad_perm(2,3,0,1)  == + lane^2
    s = dpp_add<0x141>(s);   // row_half_mirror     == + lane^4-equiv
    s = dpp_add<0x140>(s);   // row_mirror          == + lane^8-equiv
    return s;
}

// f32 -> bf16 with round-to-nearest-even (weights/features finite; no NaN path)
__device__ __forceinline__ ushort f2bf(float f) {
    unsigned u = __float_as_uint(f);
    u += 0x7FFFu + ((u >> 16) & 1u);
    return (ushort)(u >> 16);
}

// v_dot2_f32_bf16: r = acc + a.lo*b.lo + a.hi*b.hi  (bf16x2 operands)
__device__ __forceinline__ float dot2bf(unsigned a, unsigned b, float acc) {
    float r;
    asm("v_dot2_f32_bf16 %0, %1, %2, %3" : "=v"(r) : "v"(a), "v"(b), "v"(acc));
    return r;
}

// ---------------------------------------------------------------------------
// Prep: channel-last transpose [C, HW] -> [HW, C] for 6 slices.
// lf slices (0..3): packed (x, x+1) bf16 channel pairs (uint32 per channel).
// cur slices (4..5): f32.
__global__ __launch_bounds__(256) void prep_kernel(
        const float* __restrict__ cur, const float* __restrict__ lf,
        float* __restrict__ ws) {
    __shared__ float tile[32][33];   // [chLocal][nLocal 0..32] — col 32 = n0+32
    int bid = blockIdx.x;
    int slice = bid / 208;            // 208 = 104 n-blocks * 2 c-blocks
    int rem   = bid % 208;
    int nb = rem % 104, cb = rem / 104;
    const float* inS = (slice < B_ * F_)
        ? lf  + (size_t)slice * C_ * HW_
        : cur + (size_t)(slice - B_ * F_) * C_ * HW_;
    int t = threadIdx.x;
    int tx = t & 31, ty = t >> 5;
    int n0 = nb * 32, c0 = cb * 32;
    int nx = (n0 + 32 < HW_) ? (n0 + 32) : (HW_ - 1);   // clamped extra column
    #pragma unroll
    for (int k = 0; k < 32; k += 8) {
        tile[ty + k][tx] = inS[(size_t)(c0 + ty + k) * HW_ + n0 + tx];
        if (tx == 0)
            tile[ty + k][32] = inS[(size_t)(c0 + ty + k) * HW_ + nx];
    }
    __syncthreads();
    if (slice < B_ * F_) {
        // packed pair: low bf16 = value at n (x), high bf16 = value at n+1 (x+1).
        // Row-boundary pairs (x=103) pack the next row's x=0 — finite garbage,
        // only ever multiplied by weight 0 (gx <= W-2 -> x0 <= 102).
        unsigned* outS = (unsigned*)ws + (size_t)slice * HW_ * C_;
        #pragma unroll
        for (int k = 0; k < 32; k += 8) {
            unsigned lo = f2bf(tile[tx][ty + k]);
            unsigned hi = f2bf(tile[tx][ty + k + 1]);
            outS[(size_t)(n0 + ty + k) * C_ + c0 + tx] = lo | (hi << 16);
        }
    } else {
        float* outS = ws + CURT_OFF_F + (size_t)(slice - B_ * F_) * HW_ * C_;
        #pragma unroll
        for (int k = 0; k < 32; k += 8)
            outS[(size_t)(n0 + ty + k) * C_ + c0 + tx] = tile[tx][ty + k];
    }
}

// ---------------------------------------------------------------------------
// Mega kernel (R19): block = (b, y, xt) covering 4 px * ALL 96 depths * 2
// frames. 256 threads = 4 halves x (16 lanes x 4 px); each half walks 24
// depths. Phase A: 768 projections -> LDS {pre-clamped offset, uint4 weights
// {wlo, whi, mm, 0}} (projection FP op order bit-identical — mask-critical).
// Phase B: explicit distance-1 software pipeline — loads for depth d+1 issue
// before compute of depth d; two named uint4[4] stages, statically indexed,
// unconditionally written (spill-proof). dot2 bilinear, DPP reduce, v_rcp.
// Phase C: in-block missing-fill + store.
__global__ __launch_bounds__(256, 4) void mega_kernel(
        const float* __restrict__ poses, const float* __restrict__ K,
        const float* __restrict__ invK, const float* __restrict__ depth_bins,
        const float* __restrict__ ws, float* __restrict__ out) {
    int t   = threadIdx.x;
    int bid = blockIdx.x;
    int xt  = bid % XT_;  int r = bid / XT_;
    int y   = r % H_;
    int b   = r / H_;

    if (y < 2 || y >= H_ - 2) {
        // whole row masked: cost column all-zero -> column max 0 -> output 0
        for (int k = t; k < PXB * D_; k += 256) {
            int d = k >> 2, px = k & 3;
            out[((size_t)(b * D_ + d) * H_ + y) * W_ + xt * PXB + px] = 0.0f;
        }
        return;   // block-uniform exit
    }

    __shared__ alignas(16) int offsL[F_][PXB][DPADI];
    __shared__ alignas(16) uint4 wtsL[F_][PXB][DPAD];  // {wlo, whi, mm, 0}
    __shared__ float  costb[PXB][DPAD];
    __shared__ float  pmax[32][PXB];
    __shared__ float  cmaxb[PXB];

    // ---- Phase A: projections (FP op order identical to R9/R11) ----
    {
        // pads [96..99] = 0 (safe clamped offset for the Phase-B lookahead)
        if (t < 32) {
            int fp = t >> 4, pp = (t >> 2) & 3, kp = t & 3;
            offsL[fp][pp][D_ + kp] = 0;
        }
        // px = (t + 256k) & 3 = t & 3 — invariant across k. Hoist cam/interior.
        int pxA = t & 3;
        int xA  = xt * PXB + pxA;
        const float* iK = invK + (size_t)b * 16;
        float xf = (float)xA, yf = (float)y;
        float cam0 = __fmul_rn(iK[0], xf); cam0 = __fmaf_rn(iK[1], yf, cam0); cam0 = __fmaf_rn(iK[2],  1.0f, cam0);
        float cam1 = __fmul_rn(iK[4], xf); cam1 = __fmaf_rn(iK[5], yf, cam1); cam1 = __fmaf_rn(iK[6],  1.0f, cam1);
        float cam2 = __fmul_rn(iK[8], xf); cam2 = __fmaf_rn(iK[9], yf, cam2); cam2 = __fmaf_rn(iK[10], 1.0f, cam2);
        bool interior = (xA >= 2) && (xA <= W_ - 3);   // y already interior

        #pragma unroll
        for (int f = 0; f < F_; ++f) {
            const float* Kb   = K + (size_t)b * 16;
            const float* pose = poses + (size_t)(b * F_ + f) * 16;
            float P[12];
            #pragma unroll
            for (int i = 0; i < 3; ++i) {
                #pragma unroll
                for (int k = 0; k < 4; ++k) {
                    float acc = __fmul_rn(Kb[i*4+0], pose[0*4+k]);
                    acc = __fmaf_rn(Kb[i*4+1], pose[1*4+k], acc);
                    acc = __fmaf_rn(Kb[i*4+2], pose[2*4+k], acc);
                    acc = __fmaf_rn(Kb[i*4+3], pose[3*4+k], acc);
                    P[i*4+k] = acc;
                }
            }
            float vs = 0.f;
            #pragma unroll
            for (int j = 0; j < 16; ++j) vs += pose[j];
            bool valid = (vs != 0.f);

            #pragma unroll
            for (int k = 0; k < 2; ++k) {
                int idx = t + 256 * k;          // records [0,384) = dd*4 + px
                if (idx < PXB * D_) {
                    int dd = idx >> 2;
                    float depth = depth_bins[dd];
                    float p0 = __fmul_rn(depth, cam0);
                    float p1 = __fmul_rn(depth, cam1);
                    float p2 = __fmul_rn(depth, cam2);
                    float c0 = __fmul_rn(P[0], p0); c0 = __fmaf_rn(P[1], p1, c0); c0 = __fmaf_rn(P[2],  p2, c0); c0 = __fmaf_rn(P[3],  1.0f, c0);
                    float c1 = __fmul_rn(P[4], p0); c1 = __fmaf_rn(P[5], p1, c1); c1 = __fmaf_rn(P[6],  p2, c1); c1 = __fmaf_rn(P[7],  1.0f, c1);
                    float c2 = __fmul_rn(P[8], p0); c2 = __fmaf_rn(P[9], p1, c2); c2 = __fmaf_rn(P[10], p2, c2); c2 = __fmaf_rn(P[11], 1.0f, c2);
                    float denom = __fadd_rn(c2, EPSF);
                    float gx = c0 / denom;   // IEEE div — mask-critical
                    float gy = c1 / denom;
                    bool m = valid && interior && (gx >= 2.0f) && (gx <= (float)(W_ - 2))
                                               && (gy >= 2.0f) && (gy <= (float)(H_ - 2));
                    if (m) {
                        float x0f = floorf(gx), y0f = floorf(gy);
                        int   x0  = (int)x0f,   y0  = (int)y0f;
                        float wx1 = gx - x0f, wy1 = gy - y0f;
                        float wx0 = 1.f - wx1, wy0 = 1.f - wy1;
                        // packed bf16 weight pairs: low bf16 = x0 weight;
                        // .z = mm = 1/64 (mask folded into the cost scale)
                        unsigned wlo = ((unsigned)f2bf(wy0 * wx1) << 16) | f2bf(wy0 * wx0);
                        unsigned whi = ((unsigned)f2bf(wy1 * wx1) << 16) | f2bf(wy1 * wx0);
                        wtsL[f][pxA][dd] = make_uint4(wlo, whi,
                                                      __float_as_uint(1.0f / 64.0f), 0u);
                        offsL[f][pxA][dd] = (y0 * W_ + x0) * C_;   // uint32-elem offset, >=0
                    } else {
                        offsL[f][pxA][dd] = 0;       // pre-clamped safe offset
                        // mm = 0 kills the value exactly: s*0 = +0 (s finite).
                        wtsL[f][pxA][dd] = make_uint4(0u, 0u, 0u, 0u);
                    }
                }
            }
        }
    }
    __syncthreads();

    // ---- Phase B: distance-1 pipelined dwordx4 loads + dot2 + DPP reduce ----
    {
        int lane = t & 15, px = (t >> 4) & 3, half = t >> 6;  // half in [0,4)
        int x = xt * PXB + px;
        const float4 cv = *(const float4*)(ws + CURT_OFF_F
                            + ((size_t)((b * H_ + y) * W_ + x)) * C_ + lane * 4);
        // per frame: row y0 base and row y0+1 base (paired buffer, uint32 elems)
        const unsigned* pfbase = (const unsigned*)ws;
        const unsigned* pf0a = pfbase + (size_t)(b * F_ + 0) * HW_ * C_ + lane * 4;
        const unsigned* pf0b = pf0a + W_ * C_;
        const unsigned* pf1a = pfbase + (size_t)(b * F_ + 1) * HW_ * C_ + lane * 4;
        const unsigned* pf1b = pf1a + W_ * C_;

        // issue 4 corner-row loads for one depth into a named stage (uncond)
        #define ISSUE(dst, o0, o1) do {                       \
            dst[0] = *(const uint4*)(pf0a + (o0));            \
            dst[1] = *(const uint4*)(pf0b + (o0));            \
            dst[2] = *(const uint4*)(pf1a + (o1));            \
            dst[3] = *(const uint4*)(pf1b + (o1));            \
        } while (0)

        // compute one depth from a named stage; FP stream identical to R18
        // (diff = (s*1/64)*1 == s*(1/64) = s*mm; masked s*0 == +0)
        #define COMPUTE(dc, q) do {                                            \
            uint4 w0 = wtsL[0][px][dc];                                        \
            uint4 w1 = wtsL[1][px][dc];                                        \
            float s0 = dot2bf(q[1].x, w0.y, dot2bf(q[0].x, w0.x, -cv.x));      \
            float s1 = dot2bf(q[1].y, w0.y, dot2bf(q[0].y, w0.x, -cv.y));      \
            float s2 = dot2bf(q[1].z, w0.y, dot2bf(q[0].z, w0.x, -cv.z));      \
            float s3 = dot2bf(q[1].w, w0.y, dot2bf(q[0].w, w0.x, -cv.w));      \
            float sA = (fabsf(s0) + fabsf(s1)) + (fabsf(s2) + fabsf(s3));      \
            sA = group16_sum(sA);                                              \
            float u0 = dot2bf(q[3].x, w1.y, dot2bf(q[2].x, w1.x, -cv.x));      \
            float u1 = dot2bf(q[3].y, w1.y, dot2bf(q[2].y, w1.x, -cv.y));      \
            float u2 = dot2bf(q[3].z, w1.y, dot2bf(q[2].z, w1.x, -cv.z));      \
            float u3 = dot2bf(q[3].w, w1.y, dot2bf(q[2].w, w1.x, -cv.w));      \
            float sB = (fabsf(u0) + fabsf(u1)) + (fabsf(u2) + fabsf(u3));      \
            sB = group16_sum(sB);                                              \
            float diff0 = __fmul_rn(sA, __uint_as_float(w0.z));                \
            float diff1 = __fmul_rn(sB, __uint_as_float(w1.z));                \
            float costsum = diff0 + diff1;                                     \
            float counts = ((diff0 > 0.f) ? 1.0f : 0.0f)                       \
                         + ((diff1 > 0.f) ? 1.0f : 0.0f);                      \
            float cost = costsum * __builtin_amdgcn_rcpf(__fadd_rn(counts, EPSF)); \
            if (lane == 0) costb[px][dc] = cost;                               \
        } while (0)

        int dbeg = half * (D_ / 4);                       // 24 depths per half
        int4 c0v = *(const int4*)&offsL[0][px][dbeg];     // current group offsets
        int4 c1v = *(const int4*)&offsL[1][px][dbeg];
        uint4 qa[4], qb[4];                               // two pipeline stages
        ISSUE(qa, c0v.x, c1v.x);                          // prologue: depth 0

        for (int g = 0; g < 6; ++g) {                     // 6 groups of 4 depths
            int dc0 = dbeg + g * 4;
            ISSUE(qb, c0v.y, c1v.y);
            COMPUTE(dc0 + 0, qa);
            ISSUE(qa, c0v.z, c1v.z);
            COMPUTE(dc0 + 1, qb);
            ISSUE(qb, c0v.w, c1v.w);
            COMPUTE(dc0 + 2, qa);
            // next group's offsets (g=5 & half=3 -> pads [96..99] = 0, safe)
            c0v = *(const int4*)&offsL[0][px][dc0 + 4];
            c1v = *(const int4*)&offsL[1][px][dc0 + 4];
            ISSUE(qa, c0v.x, c1v.x);                      // next group depth 0
            COMPUTE(dc0 + 3, qb);
        }
        // final prefetched qa (from pad/next-half offsets) intentionally unused

        #undef ISSUE
        #undef COMPUTE
    }
    __syncthreads();

    // ---- Phase C: missing-fill + store (first 128 threads own the data) ----
    {
        int j = t >> 2, px = t & 3;          // j in [0,64); only j<32 used
        float v[3];
        if (t < 128) {
            float pm = 0.f;
            #pragma unroll
            for (int k = 0; k < 3; ++k) {
                v[k] = costb[px][j + 32 * k];
                pm = fmaxf(pm, v[k]);
            }
            pmax[j][px] = pm;
        }
        __syncthreads();
        if (t < PXB) {
            float cm = 0.f;
            #pragma unroll
            for (int jj = 0; jj < 32; ++jj) cm = fmaxf(cm, pmax[jj][t]);
            cmaxb[t] = cm;
        }
        __syncthreads();
        if (t < 128) {
            float cm = cmaxb[px];
            int x = xt * PXB + px;
            #pragma unroll
            for (int k = 0; k < 3; ++k) {
                int d = j + 32 * k;
                out[((size_t)(b * D_ + d) * H_ + y) * W_ + x] = (v[k] == 0.0f) ? cm : v[k];
            }
        }
    }
}

// ---------------------------------------------------------------------------
extern "C" void kernel_launch(void* const* d_in, const int* in_sizes, int n_in,
                              void* d_out, int out_size, void* d_ws, size_t ws_size,
                              hipStream_t stream) {
    const float* cur        = (const float*)d_in[0];  // [B,C,H,W]
    const float* lf         = (const float*)d_in[1];  // [B,F,C,H,W]
    const float* poses      = (const float*)d_in[2];  // [B,F,4,4]
    const float* K          = (const float*)d_in[3];  // [B,4,4]
    const float* invK       = (const float*)d_in[4];  // [B,4,4]
    const float* depth_bins = (const float*)d_in[5];  // [D]
    float* out = (float*)d_out;
    float* ws  = (float*)d_ws;

    prep_kernel<<<NT_BLKS, 256, 0, stream>>>(cur, lf, ws);
    mega_kernel<<<B_ * H_ * XT_, 256, 0, stream>>>(poses, K, invK, depth_bins, ws, out);
}